// Round 2
// baseline (3080.679 us; speedup 1.0000x reference)
//
#include <hip/hip_runtime.h>
#include <math.h>

// ---- problem constants (from reference) ----
constexpr int B_  = 4;
constexpr int S_  = 4096;
constexpr int D_  = 1024;   // DIM
constexpr int IN_ = 2048;   // INNER
constexpr float EPS_ = 1e-8f;
constexpr int NCH_ = 64;          // chunks per sequence for the scan
constexpr int CS_  = S_ / NCH_;   // 64 timesteps per chunk

// ---- bf16 helpers (stored as raw u16 pairs inside u32) ----
__device__ __forceinline__ float blo(unsigned u) {
  union { unsigned u; float f; } c; c.u = u << 16; return c.f;
}
__device__ __forceinline__ float bhi(unsigned u) {
  union { unsigned u; float f; } c; c.u = u & 0xffff0000u; return c.f;
}
__device__ __forceinline__ unsigned short f2bf(float f) {
  union { float f; unsigned u; } c; c.f = f;
  return (unsigned short)((c.u + 0x7fffu + ((c.u >> 16) & 1u)) >> 16);  // RNE
}
__device__ __forceinline__ unsigned packbf2(float a, float b) {
  return (unsigned)f2bf(a) | ((unsigned)f2bf(b) << 16);
}
__device__ __forceinline__ void unpack_u4(uint4 v, float* f) {
  f[0] = blo(v.x); f[1] = bhi(v.x); f[2] = blo(v.y); f[3] = bhi(v.y);
  f[4] = blo(v.z); f[5] = bhi(v.z); f[6] = blo(v.w); f[7] = bhi(v.w);
}

__device__ __forceinline__ float softplusf(float t) {
  return fmaxf(t, 0.0f) + log1pf(expf(-fabsf(t)));   // matches jax.nn.softplus
}
__device__ __forceinline__ float siluf(float x) {
  return x / (1.0f + expf(-x));
}

// ---------------------------------------------------------------------------
// NT GEMM: A (M x K, K-contig), B (N x K, K-contig), C = A@B^T + bias.
// MODE 0: A fp32 (x); output split -> xmin(bf16), silu(z)(bf16).
// MODE 1: A bf16 (G);  output fp32 + bias -> d_out.
// ---------------------------------------------------------------------------
template<int MODE>
__launch_bounds__(256)
__global__ void gemm_nt(const void* __restrict__ Ap,
                        const float* __restrict__ Bmat,
                        const float* __restrict__ bias,
                        void* __restrict__ out0p,
                        void* __restrict__ out1p,
                        int M, int N, int K)
{
  constexpr int BM = 128, BN = 128, BK = 16;
  __shared__ float As[BK][BM + 4];
  __shared__ float Bs[BK][BN + 4];
  const int m0 = blockIdx.y * BM;
  const int n0 = blockIdx.x * BN;
  const int tid = threadIdx.x;
  const int tx = tid & 15;
  const int ty = tid >> 4;
  const int lrow = tid >> 2;        // 0..63
  const int lf4  = (tid & 3) << 2;  // 0,4,8,12

  float acc[8][8];
  #pragma unroll
  for (int i = 0; i < 8; ++i)
    #pragma unroll
    for (int j = 0; j < 8; ++j) acc[i][j] = 0.0f;

  for (int k0 = 0; k0 < K; k0 += BK) {
    #pragma unroll
    for (int r = 0; r < 2; ++r) {
      const int mm = m0 + lrow + r * 64;
      float4 v;
      if (MODE == 0) {
        v = *(const float4*)((const float*)Ap + (size_t)mm * K + k0 + lf4);
      } else {
        const unsigned* A = (const unsigned*)Ap;
        const uint2 v2 = *(const uint2*)(A + ((size_t)mm * K + k0 + lf4) / 2);
        v.x = blo(v2.x); v.y = bhi(v2.x); v.z = blo(v2.y); v.w = bhi(v2.y);
      }
      As[lf4 + 0][lrow + r * 64] = v.x;
      As[lf4 + 1][lrow + r * 64] = v.y;
      As[lf4 + 2][lrow + r * 64] = v.z;
      As[lf4 + 3][lrow + r * 64] = v.w;
      const int nn = n0 + lrow + r * 64;
      const float4 w = *(const float4*)(Bmat + (size_t)nn * K + k0 + lf4);
      Bs[lf4 + 0][lrow + r * 64] = w.x;
      Bs[lf4 + 1][lrow + r * 64] = w.y;
      Bs[lf4 + 2][lrow + r * 64] = w.z;
      Bs[lf4 + 3][lrow + r * 64] = w.w;
    }
    __syncthreads();
    #pragma unroll
    for (int k = 0; k < BK; ++k) {
      float av[8], bv[8];
      *(float4*)(av)     = *(const float4*)(&As[k][ty * 8]);
      *(float4*)(av + 4) = *(const float4*)(&As[k][ty * 8 + 4]);
      *(float4*)(bv)     = *(const float4*)(&Bs[k][tx * 8]);
      *(float4*)(bv + 4) = *(const float4*)(&Bs[k][tx * 8 + 4]);
      #pragma unroll
      for (int i = 0; i < 8; ++i)
        #pragma unroll
        for (int j = 0; j < 8; ++j)
          acc[i][j] = fmaf(av[i], bv[j], acc[i][j]);
    }
    __syncthreads();
  }

  #pragma unroll
  for (int i = 0; i < 8; ++i) {
    const int mm = m0 + ty * 8 + i;
    #pragma unroll
    for (int jj = 0; jj < 8; jj += 4) {
      const int nn = n0 + tx * 8 + jj;
      float4 v;
      v.x = acc[i][jj + 0] + bias[nn + 0];
      v.y = acc[i][jj + 1] + bias[nn + 1];
      v.z = acc[i][jj + 2] + bias[nn + 2];
      v.w = acc[i][jj + 3] + bias[nn + 3];
      if (MODE == 0) {
        uint2 w2;
        if (nn < IN_) {                 // x_min half -> bf16
          w2.x = packbf2(v.x, v.y);
          w2.y = packbf2(v.z, v.w);
          *(uint2*)((unsigned*)out0p + ((size_t)mm * IN_ + nn) / 2) = w2;
        } else {                        // z half -> silu(z) bf16
          w2.x = packbf2(siluf(v.x), siluf(v.y));
          w2.y = packbf2(siluf(v.z), siluf(v.w));
          *(uint2*)((unsigned*)out1p + ((size_t)mm * IN_ + (nn - IN_)) / 2) = w2;
        }
      } else {
        *(float4*)((float*)out0p + (size_t)mm * N + nn) = v;
      }
    }
  }
}

// ---------------------------------------------------------------------------
// causal depthwise conv (K=4, left pad 3) + SiLU.  bf16 in/out, 8 ch/thread.
// ---------------------------------------------------------------------------
__launch_bounds__(256)
__global__ void conv_silu_k(const unsigned* __restrict__ xm,
                            const float* __restrict__ cw,   // (IN_,1,4)
                            const float* __restrict__ cb,
                            unsigned* __restrict__ act)
{
  const size_t total  = (size_t)B_ * S_ * IN_ / 8;
  const size_t stride = (size_t)gridDim.x * blockDim.x;
  for (size_t t = (size_t)blockIdx.x * blockDim.x + threadIdx.x; t < total; t += stride) {
    const size_t e = t * 8;
    const int    c  = (int)(e % IN_);
    const size_t bs = e / IN_;          // b*S_ + s
    const int    s  = (int)(bs % S_);
    float w[8][4];
    #pragma unroll
    for (int j = 0; j < 8; ++j)
      *(float4*)w[j] = *(const float4*)(cw + (size_t)(c + j) * 4);
    float r[8];
    *(float4*)(r)     = *(const float4*)(cb + c);
    *(float4*)(r + 4) = *(const float4*)(cb + c + 4);
    #pragma unroll
    for (int k = 0; k < 4; ++k) {
      const int ss = s - 3 + k;
      if (ss >= 0) {
        const uint4 xv = *(const uint4*)(xm + ((size_t)bs + k - 3) * (IN_ / 2) + c / 2);
        float xf[8];
        unpack_u4(xv, xf);
        #pragma unroll
        for (int j = 0; j < 8; ++j) r[j] = fmaf(xf[j], w[j][k], r[j]);
      }
    }
    uint4 o;
    o.x = packbf2(siluf(r[0]), siluf(r[1]));
    o.y = packbf2(siluf(r[2]), siluf(r[3]));
    o.z = packbf2(siluf(r[4]), siluf(r[5]));
    o.w = packbf2(siluf(r[6]), siluf(r[7]));
    *(uint4*)(act + e / 2) = o;
  }
}

// ---------------------------------------------------------------------------
// grouped 16x16 gate projections + per-chunk scan partials (act in bf16).
// ---------------------------------------------------------------------------
__launch_bounds__(256)
__global__ void gates_scan(const unsigned* __restrict__ actb,
                           const float* __restrict__ wf,
                           const float* __restrict__ wi,
                           const float* __restrict__ wh,
                           float2* __restrict__ part)   // [B_*IN_][NCH_]
{
  const int T  = blockIdx.x * 256 + threadIdx.x;
  const int o  = T & 15;
  const int g  = (T >> 4) & 127;
  const int ck = (T >> 11) & 63;
  const int b  = T >> 17;

  float Wf[16], Wi[16], Wh[16];
  const float* pf = wf + ((size_t)g * 16 + o) * 16;
  const float* pi = wi + ((size_t)g * 16 + o) * 16;
  const float* ph = wh + ((size_t)g * 16 + o) * 16;
  #pragma unroll
  for (int i = 0; i < 16; i += 4) {
    *(float4*)(Wf + i) = *(const float4*)(pf + i);
    *(float4*)(Wi + i) = *(const float4*)(pi + i);
    *(float4*)(Wh + i) = *(const float4*)(ph + i);
  }

  float p = 0.0f, Mx = -INFINITY, Ss = 0.0f;
  const unsigned* ap = actb + ((size_t)b * S_ + (size_t)ck * CS_) * (IN_ / 2) + g * 8;
  for (int s = 0; s < CS_; ++s) {
    float a[16];
    unpack_u4(*(const uint4*)(ap), a);
    unpack_u4(*(const uint4*)(ap + 4), a + 8);
    ap += IN_ / 2;
    float fg = 0.0f, ig = 0.0f, hd = 0.0f;
    #pragma unroll
    for (int i = 0; i < 16; ++i) {
      fg = fmaf(Wf[i], a[i], fg);
      ig = fmaf(Wi[i], a[i], ig);
      hd = fmaf(Wh[i], a[i], hd);
    }
    const float diff   = softplusf(-fg) - softplusf(-ig);
    const float log_f  = -softplusf(diff);
    const float log_i  = -softplusf(-diff);
    const float log_th = (hd >= 0.0f) ? logf(hd + 0.5f + EPS_)
                                      : (-softplusf(-hd) + EPS_);
    p += log_f + EPS_;
    const float v = log_i + log_th - p;
    if (v > Mx) { Ss = Ss * expf(Mx - v) + 1.0f; Mx = v; }
    else        { Ss += expf(v - Mx); }
  }
  part[((size_t)(b * IN_ + g * 16 + o)) * NCH_ + ck] = make_float2(p, Mx + logf(Ss));
}

// ---------------------------------------------------------------------------
// combine chunk partials -> h_last[b, c]
// ---------------------------------------------------------------------------
__launch_bounds__(256)
__global__ void combine_k(const float2* __restrict__ part, float* __restrict__ hlast)
{
  const int seq = blockIdx.x * 256 + threadIdx.x;
  if (seq >= B_ * IN_) return;
  const float2* pp = part + (size_t)seq * NCH_;
  float P = 0.0f, Mx = -INFINITY, Ss = 0.0f;
  for (int c = 0; c < NCH_; ++c) {
    const float2 al = pp[c];
    const float v = al.y - P;
    if (v > Mx) { Ss = Ss * expf(Mx - v) + 1.0f; Mx = v; }
    else        { Ss += expf(v - Mx); }
    P += al.x;
  }
  hlast[seq] = expf(P + Mx) * Ss;
}

// ---------------------------------------------------------------------------
// G = (h_last + skip*act) * silu(z), written in place over the z buffer.
// ---------------------------------------------------------------------------
__launch_bounds__(256)
__global__ void gfuse_k(const unsigned* __restrict__ actb,
                        unsigned* __restrict__ zb,
                        const float* __restrict__ hlast,
                        const float* __restrict__ skipv)
{
  const size_t total  = (size_t)B_ * S_ * IN_ / 8;
  const size_t stride = (size_t)gridDim.x * blockDim.x;
  for (size_t t = (size_t)blockIdx.x * blockDim.x + threadIdx.x; t < total; t += stride) {
    const size_t e = t * 8;
    const int    c = (int)(e % IN_);
    const int    b = (int)(e / ((size_t)S_ * IN_));
    float a[8], z[8], hl[8], sk[8];
    unpack_u4(*(const uint4*)(actb + e / 2), a);
    unpack_u4(*(const uint4*)(zb   + e / 2), z);
    *(float4*)(hl)     = *(const float4*)(hlast + (size_t)b * IN_ + c);
    *(float4*)(hl + 4) = *(const float4*)(hlast + (size_t)b * IN_ + c + 4);
    *(float4*)(sk)     = *(const float4*)(skipv + c);
    *(float4*)(sk + 4) = *(const float4*)(skipv + c + 4);
    float g[8];
    #pragma unroll
    for (int j = 0; j < 8; ++j) g[j] = (hl[j] + sk[j] * a[j]) * z[j];
    uint4 o;
    o.x = packbf2(g[0], g[1]);
    o.y = packbf2(g[2], g[3]);
    o.z = packbf2(g[4], g[5]);
    o.w = packbf2(g[6], g[7]);
    *(uint4*)(zb + e / 2) = o;
  }
}

// ---------------------------------------------------------------------------
extern "C" void kernel_launch(void* const* d_in, const int* in_sizes, int n_in,
                              void* d_out, int out_size, void* d_ws, size_t ws_size,
                              hipStream_t stream)
{
  const float* x     = (const float*)d_in[0];
  const float* w_up  = (const float*)d_in[1];
  const float* b_up  = (const float*)d_in[2];
  const float* cw    = (const float*)d_in[3];
  const float* cb    = (const float*)d_in[4];
  const float* skipv = (const float*)d_in[5];
  const float* w_f   = (const float*)d_in[6];
  const float* w_i   = (const float*)d_in[7];
  const float* w_h   = (const float*)d_in[8];
  const float* w_dn  = (const float*)d_in[9];
  const float* b_dn  = (const float*)d_in[10];
  float* out = (float*)d_out;

  // workspace layout (bf16 stored as u16 pairs in u32 words) -- ~196 MB total
  char* ws = (char*)d_ws;
  unsigned* xminb = (unsigned*)(ws);                    //  67,108,864 B
  unsigned* zb    = (unsigned*)(ws + 67108864ULL);      //  67,108,864 B (silu(z) -> G)
  unsigned* actb  = (unsigned*)(ws + 134217728ULL);     //  67,108,864 B
  float2*   part  = (float2*)(ws + 201326592ULL);       //   4,194,304 B
  float*    hlast = (float*)(ws + 205520896ULL);        //      32,768 B

  const int M = B_ * S_;   // 16384

  // 1) proj-up GEMM: x @ w_up^T + b_up -> xmin(bf16) | silu(z)(bf16)
  gemm_nt<0><<<dim3((2 * IN_) / 128, M / 128), 256, 0, stream>>>(
      x, w_up, b_up, xminb, zb, M, 2 * IN_, D_);

  // 2) causal depthwise conv + SiLU -> act(bf16)
  conv_silu_k<<<2048, 256, 0, stream>>>(xminb, cw, cb, actb);

  // 3) grouped gate projections + chunked scan partials
  gates_scan<<<(B_ * 128 * 16 * NCH_) / 256, 256, 0, stream>>>(actb, w_f, w_i, w_h, part);

  // 4) combine partials -> h_last
  combine_k<<<(B_ * IN_ + 255) / 256, 256, 0, stream>>>(part, hlast);

  // 5) G = (h_last + skip*act) * silu(z), in place over zb
  gfuse_k<<<2048, 256, 0, stream>>>(actb, zb, hlast, skipv);

  // 6) proj-down GEMM: G(bf16) @ w_down^T + b_down -> out (fp32)
  gemm_nt<1><<<dim3(D_ / 128, M / 128), 256, 0, stream>>>(
      zb, w_dn, b_dn, out, nullptr, M, D_, IN_);
}

// Round 3
// 992.274 us; speedup vs baseline: 3.1047x; 3.1047x over previous
//
#include <hip/hip_runtime.h>
#include <math.h>

// ---- problem constants (from reference) ----
constexpr int B_  = 4;
constexpr int S_  = 4096;
constexpr int D_  = 1024;   // DIM
constexpr int IN_ = 2048;   // INNER
constexpr float EPS_ = 1e-8f;
constexpr int NCH_ = 64;          // chunks per sequence for the scan
constexpr int CS_  = S_ / NCH_;   // 64 timesteps per chunk

typedef __attribute__((ext_vector_type(8))) __bf16 bf16x8;
typedef __attribute__((ext_vector_type(4))) float  f32x4;

// ---- bf16 helpers (raw u16 pairs inside u32) ----
__device__ __forceinline__ float blo(unsigned u) {
  union { unsigned u; float f; } c; c.u = u << 16; return c.f;
}
__device__ __forceinline__ float bhi(unsigned u) {
  union { unsigned u; float f; } c; c.u = u & 0xffff0000u; return c.f;
}
__device__ __forceinline__ unsigned short f2bf(float f) {
  union { float f; unsigned u; } c; c.f = f;
  return (unsigned short)((c.u + 0x7fffu + ((c.u >> 16) & 1u)) >> 16);  // RNE
}
__device__ __forceinline__ unsigned packbf2(float a, float b) {
  return (unsigned)f2bf(a) | ((unsigned)f2bf(b) << 16);
}
__device__ __forceinline__ void unpack_u4(uint4 v, float* f) {
  f[0] = blo(v.x); f[1] = bhi(v.x); f[2] = blo(v.y); f[3] = bhi(v.y);
  f[4] = blo(v.z); f[5] = bhi(v.z); f[6] = blo(v.w); f[7] = bhi(v.w);
}

__device__ __forceinline__ float softplusf(float t) {
  return fmaxf(t, 0.0f) + log1pf(expf(-fabsf(t)));   // matches jax.nn.softplus
}
__device__ __forceinline__ float siluf(float x) {
  return x / (1.0f + expf(-x));
}

// async global->LDS, 16 B per lane (wave-uniform LDS base + lane*16)
__device__ __forceinline__ void gload16(const void* g, void* l) {
  __builtin_amdgcn_global_load_lds(
      (const __attribute__((address_space(1))) void*)g,
      (__attribute__((address_space(3))) void*)l,
      16, 0, 0);
}

// ---------------------------------------------------------------------------
// fp32 -> bf16 conversion (8 elems/thread)
// ---------------------------------------------------------------------------
__launch_bounds__(256)
__global__ void cvt_bf16(const float* __restrict__ in, unsigned* __restrict__ outp,
                         long n8)
{
  const long stride = (long)gridDim.x * blockDim.x;
  for (long i = (long)blockIdx.x * blockDim.x + threadIdx.x; i < n8; i += stride) {
    const float4 a = *(const float4*)(in + i * 8);
    const float4 b = *(const float4*)(in + i * 8 + 4);
    uint4 o;
    o.x = packbf2(a.x, a.y);
    o.y = packbf2(a.z, a.w);
    o.z = packbf2(b.x, b.y);
    o.w = packbf2(b.z, b.w);
    *(uint4*)(outp + i * 4) = o;
  }
}

// ---------------------------------------------------------------------------
// bf16 MFMA NT GEMM: A (M x K bf16, K-contig), B (N x K bf16, K-contig),
// C = A @ B^T + bias.  128x128 tile, BK=32, 4 waves (2x2 of 64x64).
// MODE 0: split epilogue -> xmin(bf16) | silu(z)(bf16).
// MODE 1: fp32 output (d_out).
// ---------------------------------------------------------------------------
template<int MODE>
__launch_bounds__(256)
__global__ void gemm_mfma(const unsigned short* __restrict__ Ab,
                          const unsigned short* __restrict__ Bb,
                          const float* __restrict__ bias,
                          void* __restrict__ out0,
                          unsigned short* __restrict__ out1,
                          int M, int N, int K)
{
  constexpr int BM = 128, BN = 128, BK = 32;
  __shared__ __align__(16) unsigned short As[BM * BK];  // [row][k], 8 KB
  __shared__ __align__(16) unsigned short Bs[BN * BK];  // [row][k], 8 KB

  const int tid  = threadIdx.x;
  const int wid  = tid >> 6;        // 0..3
  const int lane = tid & 63;
  const int wr = wid >> 1, wc = wid & 1;
  const int m0 = blockIdx.y * BM;
  const int n0 = blockIdx.x * BN;

  // staging map: each gload16 covers 16 rows (4 lanes/row, 8 bf16/lane)
  const int srow = lane >> 2;       // 0..15
  const int skk  = (lane & 3) * 8;  // 0,8,16,24

  f32x4 acc[4][4] = {};

  // fragment read map
  const int frow = lane & 15;
  const int kg   = (lane >> 4) * 8;

  for (int k0 = 0; k0 < K; k0 += BK) {
    #pragma unroll
    for (int rb = 0; rb < 2; ++rb) {
      const int rbase = wid * 16 + rb * 64;   // wave-uniform
      gload16(Ab + (size_t)(m0 + rbase + srow) * K + k0 + skk, &As[rbase * BK]);
      gload16(Bb + (size_t)(n0 + rbase + srow) * K + k0 + skk, &Bs[rbase * BK]);
    }
    __syncthreads();
    bf16x8 af[4], bg[4];
    #pragma unroll
    for (int i = 0; i < 4; ++i) {
      af[i] = *(const bf16x8*)&As[(wr * 64 + i * 16 + frow) * BK + kg];
      bg[i] = *(const bf16x8*)&Bs[(wc * 64 + i * 16 + frow) * BK + kg];
    }
    #pragma unroll
    for (int i = 0; i < 4; ++i)
      #pragma unroll
      for (int j = 0; j < 4; ++j)
        acc[i][j] = __builtin_amdgcn_mfma_f32_16x16x32_bf16(af[i], bg[j], acc[i][j], 0, 0, 0);
    __syncthreads();
  }

  // epilogue: C/D layout col = lane&15, row = (lane>>4)*4 + r
  const int col   = lane & 15;
  const int rbase = (lane >> 4) * 4;
  #pragma unroll
  for (int j = 0; j < 4; ++j) {
    const int n  = n0 + wc * 64 + j * 16 + col;
    const float bv = bias[n];
    #pragma unroll
    for (int i = 0; i < 4; ++i) {
      const int mb = m0 + wr * 64 + i * 16 + rbase;
      #pragma unroll
      for (int r = 0; r < 4; ++r) {
        const float v = acc[i][j][r] + bv;
        const int   m = mb + r;
        if (MODE == 0) {
          if (n < IN_) {
            ((unsigned short*)out0)[(size_t)m * IN_ + n] = f2bf(v);
          } else {
            out1[(size_t)m * IN_ + (n - IN_)] = f2bf(siluf(v));
          }
        } else {
          ((float*)out0)[(size_t)m * N + n] = v;
        }
      }
    }
  }
}

// ---------------------------------------------------------------------------
// causal depthwise conv (K=4, left pad 3) + SiLU.  bf16 in/out, 8 ch/thread.
// ---------------------------------------------------------------------------
__launch_bounds__(256)
__global__ void conv_silu_k(const unsigned* __restrict__ xm,
                            const float* __restrict__ cw,   // (IN_,1,4)
                            const float* __restrict__ cb,
                            unsigned* __restrict__ act)
{
  const size_t total  = (size_t)B_ * S_ * IN_ / 8;
  const size_t stride = (size_t)gridDim.x * blockDim.x;
  for (size_t t = (size_t)blockIdx.x * blockDim.x + threadIdx.x; t < total; t += stride) {
    const size_t e = t * 8;
    const int    c  = (int)(e % IN_);
    const size_t bs = e / IN_;          // b*S_ + s
    const int    s  = (int)(bs % S_);
    float w[8][4];
    #pragma unroll
    for (int j = 0; j < 8; ++j)
      *(float4*)w[j] = *(const float4*)(cw + (size_t)(c + j) * 4);
    float r[8];
    *(float4*)(r)     = *(const float4*)(cb + c);
    *(float4*)(r + 4) = *(const float4*)(cb + c + 4);
    #pragma unroll
    for (int k = 0; k < 4; ++k) {
      const int ss = s - 3 + k;
      if (ss >= 0) {
        const uint4 xv = *(const uint4*)(xm + ((size_t)bs + k - 3) * (IN_ / 2) + c / 2);
        float xf[8];
        unpack_u4(xv, xf);
        #pragma unroll
        for (int j = 0; j < 8; ++j) r[j] = fmaf(xf[j], w[j][k], r[j]);
      }
    }
    uint4 o;
    o.x = packbf2(siluf(r[0]), siluf(r[1]));
    o.y = packbf2(siluf(r[2]), siluf(r[3]));
    o.z = packbf2(siluf(r[4]), siluf(r[5]));
    o.w = packbf2(siluf(r[6]), siluf(r[7]));
    *(uint4*)(act + e / 2) = o;
  }
}

// ---------------------------------------------------------------------------
// grouped 16x16 gate projections + per-chunk scan partials (act in bf16).
// ---------------------------------------------------------------------------
__launch_bounds__(256)
__global__ void gates_scan(const unsigned* __restrict__ actb,
                           const float* __restrict__ wf,
                           const float* __restrict__ wi,
                           const float* __restrict__ wh,
                           float2* __restrict__ part)   // [B_*IN_][NCH_]
{
  const int T  = blockIdx.x * 256 + threadIdx.x;
  const int o  = T & 15;
  const int g  = (T >> 4) & 127;
  const int ck = (T >> 11) & 63;
  const int b  = T >> 17;

  float Wf[16], Wi[16], Wh[16];
  const float* pf = wf + ((size_t)g * 16 + o) * 16;
  const float* pi = wi + ((size_t)g * 16 + o) * 16;
  const float* ph = wh + ((size_t)g * 16 + o) * 16;
  #pragma unroll
  for (int i = 0; i < 16; i += 4) {
    *(float4*)(Wf + i) = *(const float4*)(pf + i);
    *(float4*)(Wi + i) = *(const float4*)(pi + i);
    *(float4*)(Wh + i) = *(const float4*)(ph + i);
  }

  float p = 0.0f, Mx = -INFINITY, Ss = 0.0f;
  const unsigned* ap = actb + ((size_t)b * S_ + (size_t)ck * CS_) * (IN_ / 2) + g * 8;
  for (int s = 0; s < CS_; ++s) {
    float a[16];
    unpack_u4(*(const uint4*)(ap), a);
    unpack_u4(*(const uint4*)(ap + 4), a + 8);
    ap += IN_ / 2;
    float fg = 0.0f, ig = 0.0f, hd = 0.0f;
    #pragma unroll
    for (int i = 0; i < 16; ++i) {
      fg = fmaf(Wf[i], a[i], fg);
      ig = fmaf(Wi[i], a[i], ig);
      hd = fmaf(Wh[i], a[i], hd);
    }
    const float diff   = softplusf(-fg) - softplusf(-ig);
    const float log_f  = -softplusf(diff);
    const float log_i  = -softplusf(-diff);
    const float log_th = (hd >= 0.0f) ? logf(hd + 0.5f + EPS_)
                                      : (-softplusf(-hd) + EPS_);
    p += log_f + EPS_;
    const float v = log_i + log_th - p;
    if (v > Mx) { Ss = Ss * expf(Mx - v) + 1.0f; Mx = v; }
    else        { Ss += expf(v - Mx); }
  }
  part[((size_t)(b * IN_ + g * 16 + o)) * NCH_ + ck] = make_float2(p, Mx + logf(Ss));
}

// ---------------------------------------------------------------------------
// combine chunk partials -> h_last[b, c]
// ---------------------------------------------------------------------------
__launch_bounds__(256)
__global__ void combine_k(const float2* __restrict__ part, float* __restrict__ hlast)
{
  const int seq = blockIdx.x * 256 + threadIdx.x;
  if (seq >= B_ * IN_) return;
  const float2* pp = part + (size_t)seq * NCH_;
  float P = 0.0f, Mx = -INFINITY, Ss = 0.0f;
  for (int c = 0; c < NCH_; ++c) {
    const float2 al = pp[c];
    const float v = al.y - P;
    if (v > Mx) { Ss = Ss * expf(Mx - v) + 1.0f; Mx = v; }
    else        { Ss += expf(v - Mx); }
    P += al.x;
  }
  hlast[seq] = expf(P + Mx) * Ss;
}

// ---------------------------------------------------------------------------
// G = (h_last + skip*act) * silu(z), written in place over the z buffer.
// ---------------------------------------------------------------------------
__launch_bounds__(256)
__global__ void gfuse_k(const unsigned* __restrict__ actb,
                        unsigned* __restrict__ zb,
                        const float* __restrict__ hlast,
                        const float* __restrict__ skipv)
{
  const size_t total  = (size_t)B_ * S_ * IN_ / 8;
  const size_t stride = (size_t)gridDim.x * blockDim.x;
  for (size_t t = (size_t)blockIdx.x * blockDim.x + threadIdx.x; t < total; t += stride) {
    const size_t e = t * 8;
    const int    c = (int)(e % IN_);
    const int    b = (int)(e / ((size_t)S_ * IN_));
    float a[8], z[8], hl[8], sk[8];
    unpack_u4(*(const uint4*)(actb + e / 2), a);
    unpack_u4(*(const uint4*)(zb   + e / 2), z);
    *(float4*)(hl)     = *(const float4*)(hlast + (size_t)b * IN_ + c);
    *(float4*)(hl + 4) = *(const float4*)(hlast + (size_t)b * IN_ + c + 4);
    *(float4*)(sk)     = *(const float4*)(skipv + c);
    *(float4*)(sk + 4) = *(const float4*)(skipv + c + 4);
    float g[8];
    #pragma unroll
    for (int j = 0; j < 8; ++j) g[j] = (hl[j] + sk[j] * a[j]) * z[j];
    uint4 o;
    o.x = packbf2(g[0], g[1]);
    o.y = packbf2(g[2], g[3]);
    o.z = packbf2(g[4], g[5]);
    o.w = packbf2(g[6], g[7]);
    *(uint4*)(zb + e / 2) = o;
  }
}

// ---------------------------------------------------------------------------
extern "C" void kernel_launch(void* const* d_in, const int* in_sizes, int n_in,
                              void* d_out, int out_size, void* d_ws, size_t ws_size,
                              hipStream_t stream)
{
  const float* x     = (const float*)d_in[0];
  const float* w_up  = (const float*)d_in[1];
  const float* b_up  = (const float*)d_in[2];
  const float* cw    = (const float*)d_in[3];
  const float* cb    = (const float*)d_in[4];
  const float* skipv = (const float*)d_in[5];
  const float* w_f   = (const float*)d_in[6];
  const float* w_i   = (const float*)d_in[7];
  const float* w_h   = (const float*)d_in[8];
  const float* w_dn  = (const float*)d_in[9];
  const float* b_dn  = (const float*)d_in[10];
  float* out = (float*)d_out;

  // workspace layout with lifetime-based aliasing (max 209,715,200 B):
  //  [0,   67M): xminb (dead after conv) -> then wdb @0, part @8.39M, hlast @12.58M
  //  [67M, 134M): zb (silu(z) -> G in place)
  //  [134M,201M): actb;  xb (bf16 x, 33.5M) aliases this region (dead pre-conv)
  //  [201M,210M): wub
  char* ws = (char*)d_ws;
  unsigned short* xminb = (unsigned short*)(ws);
  unsigned short* wdb   = (unsigned short*)(ws);                    // after conv
  float2*         part  = (float2*)(ws + 8388608ULL);               // after conv
  float*          hlast = (float*)(ws + 12582912ULL);               // after conv
  unsigned short* zb    = (unsigned short*)(ws + 67108864ULL);
  unsigned short* actb  = (unsigned short*)(ws + 134217728ULL);
  unsigned short* xb    = (unsigned short*)(ws + 134217728ULL);     // pre-conv alias
  unsigned short* wub   = (unsigned short*)(ws + 201326592ULL);

  const int M = B_ * S_;   // 16384

  // 0) fp32 -> bf16 conversions for MFMA operands
  cvt_bf16<<<2048, 256, 0, stream>>>(x,    (unsigned*)xb,  (long)M * D_ / 8);
  cvt_bf16<<<512,  256, 0, stream>>>(w_up, (unsigned*)wub, (long)2 * IN_ * D_ / 8);

  // 1) proj-up: xb @ wub^T + b_up -> xmin(bf16) | silu(z)(bf16)
  gemm_mfma<0><<<dim3((2 * IN_) / 128, M / 128), 256, 0, stream>>>(
      xb, wub, b_up, xminb, zb, M, 2 * IN_, D_);

  // 2) causal depthwise conv + SiLU -> act(bf16)
  conv_silu_k<<<2048, 256, 0, stream>>>((const unsigned*)xminb, cw, cb, (unsigned*)actb);

  // 2b) w_down -> bf16 (into region freed by xminb)
  cvt_bf16<<<256, 256, 0, stream>>>(w_dn, (unsigned*)wdb, (long)D_ * IN_ / 8);

  // 3) grouped gate projections + chunked scan partials
  gates_scan<<<(B_ * 128 * 16 * NCH_) / 256, 256, 0, stream>>>(
      (const unsigned*)actb, w_f, w_i, w_h, part);

  // 4) combine partials -> h_last
  combine_k<<<(B_ * IN_ + 255) / 256, 256, 0, stream>>>(part, hlast);

  // 5) G = (h_last + skip*act) * silu(z), in place over zb
  gfuse_k<<<2048, 256, 0, stream>>>((const unsigned*)actb, (unsigned*)zb, hlast, skipv);

  // 6) proj-down: G(bf16) @ wdb^T + b_dn -> out (fp32)
  gemm_mfma<1><<<dim3(D_ / 128, M / 128), 256, 0, stream>>>(
      zb, wdb, b_dn, out, nullptr, M, D_, IN_);
}

// Round 5
// 600.169 us; speedup vs baseline: 5.1330x; 1.6533x over previous
//
#include <hip/hip_runtime.h>
#include <math.h>

// ---- problem constants (from reference) ----
constexpr int B_  = 4;
constexpr int S_  = 4096;
constexpr int D_  = 1024;   // DIM
constexpr int IN_ = 2048;   // INNER
constexpr float EPS_ = 1e-8f;
constexpr int NCH_ = 64;          // chunks per sequence for the scan
constexpr int CS_  = S_ / NCH_;   // 64 timesteps per chunk
constexpr float LOG2E_ = 1.4426950408889634f;
constexpr float LN2_   = 0.6931471805599453f;

typedef __attribute__((ext_vector_type(8))) _Float16 f16x8;
typedef __attribute__((ext_vector_type(2))) _Float16 h2;
typedef __attribute__((ext_vector_type(4))) float    f32x4;

// ---- helpers ----
__device__ __forceinline__ h2 pkrtz(float a, float b) {
  auto r = __builtin_amdgcn_cvt_pkrtz(a, b);     // returns __fp16 vec2
  union { decltype(r) r_; h2 h; } c; c.r_ = r; return c.h;
}
__device__ __forceinline__ unsigned packh2(float a, float b) {
  auto r = __builtin_amdgcn_cvt_pkrtz(a, b);
  union { decltype(r) r_; unsigned u; } c; c.r_ = r; return c.u;
}
__device__ __forceinline__ void unpack_h8(uint4 v, float* f) {
  union { uint4 u; _Float16 h[8]; } c; c.u = v;
  #pragma unroll
  for (int i = 0; i < 8; ++i) f[i] = (float)c.h[i];
}
__device__ __forceinline__ float spf_fast(float t) {       // softplus log(1+e^t)
  const float e = __builtin_amdgcn_exp2f(-fabsf(t) * LOG2E_);
  return fmaxf(t, 0.0f) + LN2_ * __builtin_amdgcn_logf(1.0f + e);
}
__device__ __forceinline__ float siluf(float x) {
  return x * __builtin_amdgcn_rcpf(1.0f + __builtin_amdgcn_exp2f(-x * LOG2E_));
}

// async global->LDS, 16 B per lane (wave-uniform LDS base + lane*16)
__device__ __forceinline__ void gload16(const void* g, void* l) {
  __builtin_amdgcn_global_load_lds(
      (const __attribute__((address_space(1))) void*)g,
      (__attribute__((address_space(3))) void*)l,
      16, 0, 0);
}

// ---------------------------------------------------------------------------
// fp32 -> f16 conversion (8 elems/thread)
// ---------------------------------------------------------------------------
__launch_bounds__(256)
__global__ void cvt_f16(const float* __restrict__ in, unsigned* __restrict__ outp,
                        long n8)
{
  const long stride = (long)gridDim.x * blockDim.x;
  for (long i = (long)blockIdx.x * blockDim.x + threadIdx.x; i < n8; i += stride) {
    const float4 a = *(const float4*)(in + i * 8);
    const float4 b = *(const float4*)(in + i * 8 + 4);
    uint4 o;
    o.x = packh2(a.x, a.y);
    o.y = packh2(a.z, a.w);
    o.z = packh2(b.x, b.y);
    o.w = packh2(b.z, b.w);
    *(uint4*)(outp + i * 4) = o;
  }
}

// ---------------------------------------------------------------------------
// f16 MFMA NT GEMM: A (M x K f16, K-contig), B (N x K f16, K-contig),
// C = A @ B^T + bias.  128x128 tile, BK=32, 4 waves (2x2 of 64x64).
// MODE 0: split epilogue -> xmin(f16) | silu(z)(f16).   MODE 1: fp32 out.
// ---------------------------------------------------------------------------
template<int MODE>
__launch_bounds__(256)
__global__ void gemm_mfma(const unsigned short* __restrict__ Ab,
                          const unsigned short* __restrict__ Bb,
                          const float* __restrict__ bias,
                          void* __restrict__ out0,
                          unsigned short* __restrict__ out1,
                          int M, int N, int K)
{
  constexpr int BM = 128, BN = 128, BK = 32;
  __shared__ __align__(16) unsigned short As[BM * BK];  // [row][k], 8 KB
  __shared__ __align__(16) unsigned short Bs[BN * BK];  // [row][k], 8 KB

  const int tid  = threadIdx.x;
  const int wid  = tid >> 6;        // 0..3
  const int lane = tid & 63;
  const int wr = wid >> 1, wc = wid & 1;
  const int m0 = blockIdx.y * BM;
  const int n0 = blockIdx.x * BN;

  const int srow = lane >> 2;       // 0..15
  const int skk  = (lane & 3) * 8;  // 0,8,16,24

  f32x4 acc[4][4] = {};

  const int frow = lane & 15;
  const int kg   = (lane >> 4) * 8;

  for (int k0 = 0; k0 < K; k0 += BK) {
    #pragma unroll
    for (int rb = 0; rb < 2; ++rb) {
      const int rbase = wid * 16 + rb * 64;   // wave-uniform
      gload16(Ab + (size_t)(m0 + rbase + srow) * K + k0 + skk, &As[rbase * BK]);
      gload16(Bb + (size_t)(n0 + rbase + srow) * K + k0 + skk, &Bs[rbase * BK]);
    }
    __syncthreads();
    f16x8 af[4], bg[4];
    #pragma unroll
    for (int i = 0; i < 4; ++i) {
      af[i] = *(const f16x8*)&As[(wr * 64 + i * 16 + frow) * BK + kg];
      bg[i] = *(const f16x8*)&Bs[(wc * 64 + i * 16 + frow) * BK + kg];
    }
    #pragma unroll
    for (int i = 0; i < 4; ++i)
      #pragma unroll
      for (int j = 0; j < 4; ++j)
        acc[i][j] = __builtin_amdgcn_mfma_f32_16x16x32_f16(af[i], bg[j], acc[i][j], 0, 0, 0);
    __syncthreads();
  }

  // epilogue: C/D layout col = lane&15, row = (lane>>4)*4 + r
  const int col   = lane & 15;
  const int rbase = (lane >> 4) * 4;
  #pragma unroll
  for (int j = 0; j < 4; ++j) {
    const int n  = n0 + wc * 64 + j * 16 + col;
    const float bv = bias[n];
    #pragma unroll
    for (int i = 0; i < 4; ++i) {
      const int mb = m0 + wr * 64 + i * 16 + rbase;
      #pragma unroll
      for (int r = 0; r < 4; ++r) {
        const float v = acc[i][j][r] + bv;
        const int   m = mb + r;
        if (MODE == 0) {
          if (n < IN_) {
            ((_Float16*)out0)[(size_t)m * IN_ + n] = (_Float16)v;
          } else {
            ((_Float16*)out1)[(size_t)m * IN_ + (n - IN_)] = (_Float16)siluf(v);
          }
        } else {
          ((float*)out0)[(size_t)m * N + n] = v;
        }
      }
    }
  }
}

// ---------------------------------------------------------------------------
// causal depthwise conv (K=4, left pad 3) + SiLU.  f16 in/out, 8 ch/thread.
// ---------------------------------------------------------------------------
__launch_bounds__(256)
__global__ void conv_silu_k(const unsigned* __restrict__ xm,
                            const float* __restrict__ cw,   // (IN_,1,4)
                            const float* __restrict__ cb,
                            unsigned* __restrict__ act)
{
  const size_t total  = (size_t)B_ * S_ * IN_ / 8;
  const size_t stride = (size_t)gridDim.x * blockDim.x;
  for (size_t t = (size_t)blockIdx.x * blockDim.x + threadIdx.x; t < total; t += stride) {
    const size_t e = t * 8;
    const int    c  = (int)(e % IN_);
    const size_t bs = e / IN_;          // b*S_ + s
    const int    s  = (int)(bs % S_);
    float w[8][4];
    #pragma unroll
    for (int j = 0; j < 8; ++j)
      *(float4*)w[j] = *(const float4*)(cw + (size_t)(c + j) * 4);
    float r[8];
    *(float4*)(r)     = *(const float4*)(cb + c);
    *(float4*)(r + 4) = *(const float4*)(cb + c + 4);
    #pragma unroll
    for (int k = 0; k < 4; ++k) {
      const int ss = s - 3 + k;
      if (ss >= 0) {
        const uint4 xv = *(const uint4*)(xm + ((size_t)bs + k - 3) * (IN_ / 2) + c / 2);
        float xf[8];
        unpack_h8(xv, xf);
        #pragma unroll
        for (int j = 0; j < 8; ++j) r[j] = fmaf(xf[j], w[j][k], r[j]);
      }
    }
    uint4 o;
    o.x = packh2(siluf(r[0]), siluf(r[1]));
    o.y = packh2(siluf(r[2]), siluf(r[3]));
    o.z = packh2(siluf(r[4]), siluf(r[5]));
    o.w = packh2(siluf(r[6]), siluf(r[7]));
    *(uint4*)(act + e / 2) = o;
  }
}

// ---------------------------------------------------------------------------
// grouped 16x16 gate projections + per-chunk scan partials.
// act in f16; dots via v_dot2_f32_f16; fast exp2/log2 log-math; branchless LSE.
// ---------------------------------------------------------------------------
__launch_bounds__(256)
__global__ void gates_scan(const unsigned* __restrict__ actb,
                           const float* __restrict__ wf,
                           const float* __restrict__ wi,
                           const float* __restrict__ wh,
                           float2* __restrict__ part)   // [B_*IN_][NCH_]
{
  const int T  = blockIdx.x * 256 + threadIdx.x;
  const int o  = T & 15;
  const int g  = (T >> 4) & 127;
  const int ck = (T >> 11) & 63;
  const int b  = T >> 17;

  h2 Wf2[8], Wi2[8], Wh2[8];
  const float* pf = wf + ((size_t)g * 16 + o) * 16;
  const float* pi = wi + ((size_t)g * 16 + o) * 16;
  const float* ph = wh + ((size_t)g * 16 + o) * 16;
  #pragma unroll
  for (int i = 0; i < 8; ++i) {
    Wf2[i] = pkrtz(pf[2 * i], pf[2 * i + 1]);
    Wi2[i] = pkrtz(pi[2 * i], pi[2 * i + 1]);
    Wh2[i] = pkrtz(ph[2 * i], ph[2 * i + 1]);
  }

  float p = 0.0f, Mx = -INFINITY, Ss = 0.0f;
  const unsigned* ap = actb + ((size_t)b * S_ + (size_t)ck * CS_) * (IN_ / 2) + g * 8;
  for (int s = 0; s < CS_; ++s) {
    union { uint4 u; h2 h[4]; } A0, A1;
    A0.u = *(const uint4*)(ap);
    A1.u = *(const uint4*)(ap + 4);
    ap += IN_ / 2;
    float fg = 0.0f, ig = 0.0f, hd = 0.0f;
    #pragma unroll
    for (int i = 0; i < 4; ++i) {
      fg = __builtin_amdgcn_fdot2(A0.h[i], Wf2[i], fg, false);
      ig = __builtin_amdgcn_fdot2(A0.h[i], Wi2[i], ig, false);
      hd = __builtin_amdgcn_fdot2(A0.h[i], Wh2[i], hd, false);
    }
    #pragma unroll
    for (int i = 0; i < 4; ++i) {
      fg = __builtin_amdgcn_fdot2(A1.h[i], Wf2[i + 4], fg, false);
      ig = __builtin_amdgcn_fdot2(A1.h[i], Wi2[i + 4], ig, false);
      hd = __builtin_amdgcn_fdot2(A1.h[i], Wh2[i + 4], hd, false);
    }
    const float diff  = spf_fast(-fg) - spf_fast(-ig);
    const float log_f = -spf_fast(diff);
    const float log_i = diff + log_f;          // sp(-d) = sp(d) - d
    const float lpos  = LN2_ * __builtin_amdgcn_logf(hd + 0.5f + EPS_);
    const float lneg  = -spf_fast(-hd) + EPS_;
    const float log_th = (hd >= 0.0f) ? lpos : lneg;
    p += log_f + EPS_;
    const float v = log_i + log_th - p;
    const float m = fmaxf(Mx, v);
    Ss = Ss * __builtin_amdgcn_exp2f((Mx - m) * LOG2E_)
       + __builtin_amdgcn_exp2f((v - m) * LOG2E_);
    Mx = m;
  }
  part[((size_t)(b * IN_ + g * 16 + o)) * NCH_ + ck] =
      make_float2(p, Mx + LN2_ * __builtin_amdgcn_logf(Ss));
}

// ---------------------------------------------------------------------------
// combine chunk partials -> h_last[b, c]
// ---------------------------------------------------------------------------
__launch_bounds__(256)
__global__ void combine_k(const float2* __restrict__ part, float* __restrict__ hlast)
{
  const int seq = blockIdx.x * 256 + threadIdx.x;
  if (seq >= B_ * IN_) return;
  const float2* pp = part + (size_t)seq * NCH_;
  float P = 0.0f, Mx = -INFINITY, Ss = 0.0f;
  for (int c = 0; c < NCH_; ++c) {
    const float2 al = pp[c];
    const float v = al.y - P;
    const float m = fmaxf(Mx, v);
    Ss = Ss * __builtin_amdgcn_exp2f((Mx - m) * LOG2E_)
       + __builtin_amdgcn_exp2f((v - m) * LOG2E_);
    Mx = m;
    P += al.x;
  }
  hlast[seq] = __builtin_amdgcn_exp2f((P + Mx) * LOG2E_) * Ss;
}

// ---------------------------------------------------------------------------
// G = (h_last + skip*act) * silu(z), written in place over the z buffer.
// ---------------------------------------------------------------------------
__launch_bounds__(256)
__global__ void gfuse_k(const unsigned* __restrict__ actb,
                        unsigned* __restrict__ zb,
                        const float* __restrict__ hlast,
                        const float* __restrict__ skipv)
{
  const size_t total  = (size_t)B_ * S_ * IN_ / 8;
  const size_t stride = (size_t)gridDim.x * blockDim.x;
  for (size_t t = (size_t)blockIdx.x * blockDim.x + threadIdx.x; t < total; t += stride) {
    const size_t e = t * 8;
    const int    c = (int)(e % IN_);
    const int    b = (int)(e / ((size_t)S_ * IN_));
    float a[8], z[8], hl[8], sk[8];
    unpack_h8(*(const uint4*)(actb + e / 2), a);
    unpack_h8(*(const uint4*)(zb   + e / 2), z);
    *(float4*)(hl)     = *(const float4*)(hlast + (size_t)b * IN_ + c);
    *(float4*)(hl + 4) = *(const float4*)(hlast + (size_t)b * IN_ + c + 4);
    *(float4*)(sk)     = *(const float4*)(skipv + c);
    *(float4*)(sk + 4) = *(const float4*)(skipv + c + 4);
    float g[8];
    #pragma unroll
    for (int j = 0; j < 8; ++j) g[j] = (hl[j] + sk[j] * a[j]) * z[j];
    uint4 o;
    o.x = packh2(g[0], g[1]);
    o.y = packh2(g[2], g[3]);
    o.z = packh2(g[4], g[5]);
    o.w = packh2(g[6], g[7]);
    *(uint4*)(zb + e / 2) = o;
  }
}

// ---------------------------------------------------------------------------
extern "C" void kernel_launch(void* const* d_in, const int* in_sizes, int n_in,
                              void* d_out, int out_size, void* d_ws, size_t ws_size,
                              hipStream_t stream)
{
  const float* x     = (const float*)d_in[0];
  const float* w_up  = (const float*)d_in[1];
  const float* b_up  = (const float*)d_in[2];
  const float* cw    = (const float*)d_in[3];
  const float* cb    = (const float*)d_in[4];
  const float* skipv = (const float*)d_in[5];
  const float* w_f   = (const float*)d_in[6];
  const float* w_i   = (const float*)d_in[7];
  const float* w_h   = (const float*)d_in[8];
  const float* w_dn  = (const float*)d_in[9];
  const float* b_dn  = (const float*)d_in[10];
  float* out = (float*)d_out;

  // workspace layout with lifetime-based aliasing (max ~210 MB):
  //  [0,   67M): xminb (dead after conv) -> then wdb @0, part @8.39M, hlast @12.58M
  //  [67M, 134M): zb (silu(z) -> G in place)
  //  [134M,201M): actb;  xb (f16 x, 33.5M) aliases this region (dead pre-conv)
  //  [201M,210M): wub
  char* ws = (char*)d_ws;
  unsigned short* xminb = (unsigned short*)(ws);
  unsigned short* wdb   = (unsigned short*)(ws);                    // after conv
  float2*         part  = (float2*)(ws + 8388608ULL);               // after conv
  float*          hlast = (float*)(ws + 12582912ULL);               // after conv
  unsigned short* zb    = (unsigned short*)(ws + 67108864ULL);
  unsigned short* actb  = (unsigned short*)(ws + 134217728ULL);
  unsigned short* xb    = (unsigned short*)(ws + 134217728ULL);     // pre-conv alias
  unsigned short* wub   = (unsigned short*)(ws + 201326592ULL);

  const int M = B_ * S_;   // 16384

  // 0) fp32 -> f16 conversions for MFMA operands
  cvt_f16<<<2048, 256, 0, stream>>>(x,    (unsigned*)xb,  (long)M * D_ / 8);
  cvt_f16<<<512,  256, 0, stream>>>(w_up, (unsigned*)wub, (long)2 * IN_ * D_ / 8);

  // 1) proj-up: xb @ wub^T + b_up -> xmin(f16) | silu(z)(f16)
  gemm_mfma<0><<<dim3((2 * IN_) / 128, M / 128), 256, 0, stream>>>(
      xb, wub, b_up, xminb, (unsigned short*)zb, M, 2 * IN_, D_);

  // 2) causal depthwise conv + SiLU -> act(f16)
  conv_silu_k<<<2048, 256, 0, stream>>>((const unsigned*)xminb, cw, cb, (unsigned*)actb);

  // 2b) w_down -> f16 (into region freed by xminb)
  cvt_f16<<<256, 256, 0, stream>>>(w_dn, (unsigned*)wdb, (long)D_ * IN_ / 8);

  // 3) grouped gate projections + chunked scan partials
  gates_scan<<<(B_ * 128 * 16 * NCH_) / 256, 256, 0, stream>>>(
      (const unsigned*)actb, w_f, w_i, w_h, part);

  // 4) combine partials -> h_last
  combine_k<<<(B_ * IN_ + 255) / 256, 256, 0, stream>>>(part, hlast);

  // 5) G = (h_last + skip*act) * silu(z), in place over zb
  gfuse_k<<<2048, 256, 0, stream>>>((const unsigned*)actb, (unsigned*)zb, hlast, skipv);

  // 6) proj-down: G(f16) @ wdb^T + b_dn -> out (fp32)
  gemm_mfma<1><<<dim3(D_ / 128, M / 128), 256, 0, stream>>>(
      zb, wdb, b_dn, out, nullptr, M, D_, IN_);
}

// Round 6
// 541.738 us; speedup vs baseline: 5.6867x; 1.1079x over previous
//
#include <hip/hip_runtime.h>
#include <math.h>

// ---- problem constants (from reference) ----
constexpr int B_  = 4;
constexpr int S_  = 4096;
constexpr int D_  = 1024;   // DIM
constexpr int IN_ = 2048;   // INNER
constexpr float EPS_ = 1e-8f;
constexpr int NCH_ = 128;         // chunks per sequence for the scan
constexpr int CS_  = S_ / NCH_;   // 32 timesteps per chunk
constexpr float LOG2E_ = 1.4426950408889634f;
constexpr float LN2_   = 0.6931471805599453f;

typedef __attribute__((ext_vector_type(8))) _Float16 f16x8;
typedef __attribute__((ext_vector_type(2))) _Float16 h2;
typedef __attribute__((ext_vector_type(4))) float    f32x4;

#define BAR() asm volatile("s_barrier" ::: "memory")

// ---- helpers ----
__device__ __forceinline__ h2 pkrtz(float a, float b) {
  auto r = __builtin_amdgcn_cvt_pkrtz(a, b);
  union { decltype(r) r_; h2 h; } c; c.r_ = r; return c.h;
}
__device__ __forceinline__ unsigned packh2(float a, float b) {
  auto r = __builtin_amdgcn_cvt_pkrtz(a, b);
  union { decltype(r) r_; unsigned u; } c; c.r_ = r; return c.u;
}
__device__ __forceinline__ void unpack_h8(uint4 v, float* f) {
  union { uint4 u; _Float16 h[8]; } c; c.u = v;
  #pragma unroll
  for (int i = 0; i < 8; ++i) f[i] = (float)c.h[i];
}
__device__ __forceinline__ float spf_fast(float t) {       // softplus log(1+e^t)
  const float e = __builtin_amdgcn_exp2f(-fabsf(t) * LOG2E_);
  return fmaxf(t, 0.0f) + LN2_ * __builtin_amdgcn_logf(1.0f + e);
}
__device__ __forceinline__ float siluf(float x) {
  return x * __builtin_amdgcn_rcpf(1.0f + __builtin_amdgcn_exp2f(-x * LOG2E_));
}

// async global->LDS, 16 B per lane (wave-uniform LDS base + lane*16)
__device__ __forceinline__ void gload16(const void* g, void* l) {
  __builtin_amdgcn_global_load_lds(
      (const __attribute__((address_space(1))) void*)g,
      (__attribute__((address_space(3))) void*)l,
      16, 0, 0);
}

// ---------------------------------------------------------------------------
// fp32 -> f16 conversion (8 elems/thread)
// ---------------------------------------------------------------------------
__launch_bounds__(256)
__global__ void cvt_f16(const float* __restrict__ in, unsigned* __restrict__ outp,
                        long n8)
{
  const long stride = (long)gridDim.x * blockDim.x;
  for (long i = (long)blockIdx.x * blockDim.x + threadIdx.x; i < n8; i += stride) {
    const float4 a = *(const float4*)(in + i * 8);
    const float4 b = *(const float4*)(in + i * 8 + 4);
    uint4 o;
    o.x = packh2(a.x, a.y);
    o.y = packh2(a.z, a.w);
    o.z = packh2(b.x, b.y);
    o.w = packh2(b.z, b.w);
    *(uint4*)(outp + i * 4) = o;
  }
}

// ---------------------------------------------------------------------------
// f16 MFMA NT GEMM, 8-phase-style schedule:
//   256x256 tile, BK=64, 8 waves (2M x 4N), per-wave C = 128x64 (8x4 frags).
//   Double-buffered LDS (128 KiB), XOR-16B-block swizzle (blk ^= row&7)
//   applied via pre-swizzled GLOBAL source (linear global_load_lds dest) and
//   the same XOR on ds_read. 4 phases per K-tile: quadrant (mq,nq) with
//   16 MFMA each, 2 raw barriers per phase, tile t+2 staged in phases 2-3
//   into the just-freed halves, counted vmcnt(8) once per K-tile.
// MODE 0: split epilogue -> xmin(f16) | silu(z)(f16).   MODE 1: fp32 out.
// ---------------------------------------------------------------------------
template<int MODE>
__launch_bounds__(512, 2)
__global__ void gemm_mfma(const unsigned short* __restrict__ Ab,
                          const unsigned short* __restrict__ Bb,
                          const float* __restrict__ bias,
                          void* __restrict__ out0,
                          unsigned short* __restrict__ out1,
                          int M, int N, int K)
{
  constexpr int BM = 256, BN = 256, BK = 64;
  __shared__ __align__(16) unsigned short As[2][BM * BK];  // 2 x 32 KB
  __shared__ __align__(16) unsigned short Bs[2][BN * BK];  // 2 x 32 KB

  const int tid  = threadIdx.x;
  const int lane = tid & 63;
  const int w    = tid >> 6;       // 0..7
  const int wm   = w >> 2;         // 0..1  (M half)
  const int wn   = w & 3;          // 0..3  (N quarter)
  const int m0 = blockIdx.y * BM;
  const int n0 = blockIdx.x * BN;
  const int NT = K / BK;

  // staging geometry: one call = 64 rows; wave w covers rows c*64+w*8 .. +7
  const int sr   = lane >> 3;                   // 0..7 row-in-slice
  const int sblk = ((lane & 7) ^ sr) * 8;       // pre-swizzled global col (elems)

  // fragment read geometry: row&7 == lane&7 for all fragment rows
  const int fr  = lane & 15;
  const int fb0 = (((lane >> 4) + 0) ^ (lane & 7)) * 8;   // k-step 0
  const int fb1 = (((lane >> 4) + 4) ^ (lane & 7)) * 8;   // k-step 1

  auto stage64 = [&](const unsigned short* Gp, int Kd, int grow0, int kOff,
                     unsigned short* lchunk) {
    gload16(Gp + (size_t)(grow0 + w * 8 + sr) * Kd + kOff + sblk,
            lchunk + (w * 8) * BK);
  };

  f32x4 acc[8][4] = {};

  // ---- prologue: stage tiles 0 and 1 ----
  #pragma unroll
  for (int c = 0; c < 4; ++c) stage64(Ab, K, m0 + c * 64, 0, &As[0][c * 64 * BK]);
  #pragma unroll
  for (int c = 0; c < 4; ++c) stage64(Bb, K, n0 + c * 64, 0, &Bs[0][c * 64 * BK]);
  #pragma unroll
  for (int c = 0; c < 4; ++c) stage64(Ab, K, m0 + c * 64, BK, &As[1][c * 64 * BK]);
  #pragma unroll
  for (int c = 0; c < 4; ++c) stage64(Bb, K, n0 + c * 64, BK, &Bs[1][c * 64 * BK]);
  asm volatile("s_waitcnt vmcnt(8)" ::: "memory");   // tile 0 landed
  BAR();

  for (int t = 0; t < NT; ++t) {
    const int cur = t & 1;
    const unsigned short* AL = As[cur];
    const unsigned short* BL = Bs[cur];
    const int  nxtK = (t + 2) * BK;
    const bool more = (t + 2 < NT);

    f16x8 af[4][2], bf[4][2];

    // ---- phase 0: quadrant (mq=0, nq=0) — 12 ds_reads, 16 MFMA
    #pragma unroll
    for (int i = 0; i < 4; ++i) {
      const int row = wm * 128 + i * 16 + fr;
      af[i][0] = *(const f16x8*)&AL[row * BK + fb0];
      af[i][1] = *(const f16x8*)&AL[row * BK + fb1];
    }
    #pragma unroll
    for (int j = 0; j < 2; ++j) {
      const int row = wn * 64 + j * 16 + fr;
      bf[j][0] = *(const f16x8*)&BL[row * BK + fb0];
      bf[j][1] = *(const f16x8*)&BL[row * BK + fb1];
    }
    BAR();
    __builtin_amdgcn_s_setprio(1);
    #pragma unroll
    for (int i = 0; i < 4; ++i)
      #pragma unroll
      for (int j = 0; j < 2; ++j) {
        acc[i][j] = __builtin_amdgcn_mfma_f32_16x16x32_f16(af[i][0], bf[j][0], acc[i][j], 0, 0, 0);
        acc[i][j] = __builtin_amdgcn_mfma_f32_16x16x32_f16(af[i][1], bf[j][1], acc[i][j], 0, 0, 0);
      }
    __builtin_amdgcn_s_setprio(0);
    BAR();

    // ---- phase 1: (mq=0, nq=1) — 4 ds_reads, 16 MFMA
    #pragma unroll
    for (int j = 2; j < 4; ++j) {
      const int row = wn * 64 + j * 16 + fr;
      bf[j][0] = *(const f16x8*)&BL[row * BK + fb0];
      bf[j][1] = *(const f16x8*)&BL[row * BK + fb1];
    }
    BAR();
    __builtin_amdgcn_s_setprio(1);
    #pragma unroll
    for (int i = 0; i < 4; ++i)
      #pragma unroll
      for (int j = 2; j < 4; ++j) {
        acc[i][j] = __builtin_amdgcn_mfma_f32_16x16x32_f16(af[i][0], bf[j][0], acc[i][j], 0, 0, 0);
        acc[i][j] = __builtin_amdgcn_mfma_f32_16x16x32_f16(af[i][1], bf[j][1], acc[i][j], 0, 0, 0);
      }
    __builtin_amdgcn_s_setprio(0);
    BAR();

    // ---- phase 2: (mq=1, nq=0) — 8 ds_reads; stage B rows 0-127 of t+2
    //      (B[cur] rows fully consumed at end of phase 1)
    #pragma unroll
    for (int i = 0; i < 4; ++i) {
      const int row = wm * 128 + 64 + i * 16 + fr;
      af[i][0] = *(const f16x8*)&AL[row * BK + fb0];
      af[i][1] = *(const f16x8*)&AL[row * BK + fb1];
    }
    if (more) {
      stage64(Bb, K, n0 +  0, nxtK, &Bs[cur][0]);
      stage64(Bb, K, n0 + 64, nxtK, &Bs[cur][64 * BK]);
    }
    BAR();
    __builtin_amdgcn_s_setprio(1);
    #pragma unroll
    for (int i = 0; i < 4; ++i)
      #pragma unroll
      for (int j = 0; j < 2; ++j) {
        acc[4 + i][j] = __builtin_amdgcn_mfma_f32_16x16x32_f16(af[i][0], bf[j][0], acc[4 + i][j], 0, 0, 0);
        acc[4 + i][j] = __builtin_amdgcn_mfma_f32_16x16x32_f16(af[i][1], bf[j][1], acc[4 + i][j], 0, 0, 0);
      }
    __builtin_amdgcn_s_setprio(0);
    BAR();

    // ---- phase 3: (mq=1, nq=1) — 0 ds_reads; stage B rows 128-255 + all A of t+2
    //      (A[cur] fully consumed at end of phase 2)
    if (more) {
      stage64(Bb, K, n0 + 128, nxtK, &Bs[cur][128 * BK]);
      stage64(Bb, K, n0 + 192, nxtK, &Bs[cur][192 * BK]);
      #pragma unroll
      for (int c = 0; c < 4; ++c) stage64(Ab, K, m0 + c * 64, nxtK, &As[cur][c * 64 * BK]);
    }
    BAR();
    __builtin_amdgcn_s_setprio(1);
    #pragma unroll
    for (int i = 0; i < 4; ++i)
      #pragma unroll
      for (int j = 2; j < 4; ++j) {
        acc[4 + i][j] = __builtin_amdgcn_mfma_f32_16x16x32_f16(af[i][0], bf[j][0], acc[4 + i][j], 0, 0, 0);
        acc[4 + i][j] = __builtin_amdgcn_mfma_f32_16x16x32_f16(af[i][1], bf[j][1], acc[4 + i][j], 0, 0, 0);
      }
    __builtin_amdgcn_s_setprio(0);
    // tile t+1 ready-check: its last staging instr was iter t-1 phase 3;
    // exactly the 8 instrs of tile t+2 (issued this iteration) may remain.
    if (more) asm volatile("s_waitcnt vmcnt(8)" ::: "memory");
    else      asm volatile("s_waitcnt vmcnt(0)" ::: "memory");
    BAR();
  }

  // ---- epilogue: C/D layout col = lane&15, row = (lane>>4)*4 + r
  const int col = lane & 15;
  const int rb4 = (lane >> 4) * 4;
  #pragma unroll
  for (int j = 0; j < 4; ++j) {
    const int n  = n0 + wn * 64 + j * 16 + col;
    const float bv = bias[n];
    #pragma unroll
    for (int i = 0; i < 8; ++i) {
      const int mb = m0 + wm * 128 + i * 16 + rb4;
      #pragma unroll
      for (int r = 0; r < 4; ++r) {
        const float v = acc[i][j][r] + bv;
        const int   m = mb + r;
        if (MODE == 0) {
          if (n < IN_) {
            ((_Float16*)out0)[(size_t)m * IN_ + n] = (_Float16)v;
          } else {
            ((_Float16*)out1)[(size_t)m * IN_ + (n - IN_)] = (_Float16)siluf(v);
          }
        } else {
          ((float*)out0)[(size_t)m * N + n] = v;
        }
      }
    }
  }
}

// ---------------------------------------------------------------------------
// causal depthwise conv (K=4, left pad 3) + SiLU.  f16 in/out, 8 ch/thread.
// ---------------------------------------------------------------------------
__launch_bounds__(256)
__global__ void conv_silu_k(const unsigned* __restrict__ xm,
                            const float* __restrict__ cw,   // (IN_,1,4)
                            const float* __restrict__ cb,
                            unsigned* __restrict__ act)
{
  const size_t total  = (size_t)B_ * S_ * IN_ / 8;
  const size_t stride = (size_t)gridDim.x * blockDim.x;
  for (size_t t = (size_t)blockIdx.x * blockDim.x + threadIdx.x; t < total; t += stride) {
    const size_t e = t * 8;
    const int    c  = (int)(e % IN_);
    const size_t bs = e / IN_;          // b*S_ + s
    const int    s  = (int)(bs % S_);
    float w[8][4];
    #pragma unroll
    for (int j = 0; j < 8; ++j)
      *(float4*)w[j] = *(const float4*)(cw + (size_t)(c + j) * 4);
    float r[8];
    *(float4*)(r)     = *(const float4*)(cb + c);
    *(float4*)(r + 4) = *(const float4*)(cb + c + 4);
    #pragma unroll
    for (int k = 0; k < 4; ++k) {
      const int ss = s - 3 + k;
      if (ss >= 0) {
        const uint4 xv = *(const uint4*)(xm + ((size_t)bs + k - 3) * (IN_ / 2) + c / 2);
        float xf[8];
        unpack_h8(xv, xf);
        #pragma unroll
        for (int j = 0; j < 8; ++j) r[j] = fmaf(xf[j], w[j][k], r[j]);
      }
    }
    uint4 o;
    o.x = packh2(siluf(r[0]), siluf(r[1]));
    o.y = packh2(siluf(r[2]), siluf(r[3]));
    o.z = packh2(siluf(r[4]), siluf(r[5]));
    o.w = packh2(siluf(r[6]), siluf(r[7]));
    *(uint4*)(act + e / 2) = o;
  }
}

// ---------------------------------------------------------------------------
// grouped 16x16 gate projections + per-chunk scan partials.
// act in f16; dots via v_dot2_f32_f16; fast exp2/log2 log-math; branchless LSE.
// ---------------------------------------------------------------------------
__launch_bounds__(256)
__global__ void gates_scan(const unsigned* __restrict__ actb,
                           const float* __restrict__ wf,
                           const float* __restrict__ wi,
                           const float* __restrict__ wh,
                           float2* __restrict__ part)   // [B_*IN_][NCH_]
{
  const int T  = blockIdx.x * 256 + threadIdx.x;
  const int o  = T & 15;
  const int g  = (T >> 4) & 127;
  const int ck = (T >> 11) & (NCH_ - 1);
  const int b  = T >> 18;

  h2 Wf2[8], Wi2[8], Wh2[8];
  const float* pf = wf + ((size_t)g * 16 + o) * 16;
  const float* pi = wi + ((size_t)g * 16 + o) * 16;
  const float* ph = wh + ((size_t)g * 16 + o) * 16;
  #pragma unroll
  for (int i = 0; i < 8; ++i) {
    Wf2[i] = pkrtz(pf[2 * i], pf[2 * i + 1]);
    Wi2[i] = pkrtz(pi[2 * i], pi[2 * i + 1]);
    Wh2[i] = pkrtz(ph[2 * i], ph[2 * i + 1]);
  }

  float p = 0.0f, Mx = -INFINITY, Ss = 0.0f;
  const unsigned* ap = actb + ((size_t)b * S_ + (size_t)ck * CS_) * (IN_ / 2) + g * 8;
  for (int s = 0; s < CS_; ++s) {
    union { uint4 u; h2 h[4]; } A0, A1;
    A0.u = *(const uint4*)(ap);
    A1.u = *(const uint4*)(ap + 4);
    ap += IN_ / 2;
    float fg = 0.0f, ig = 0.0f, hd = 0.0f;
    #pragma unroll
    for (int i = 0; i < 4; ++i) {
      fg = __builtin_amdgcn_fdot2(A0.h[i], Wf2[i], fg, false);
      ig = __builtin_amdgcn_fdot2(A0.h[i], Wi2[i], ig, false);
      hd = __builtin_amdgcn_fdot2(A0.h[i], Wh2[i], hd, false);
    }
    #pragma unroll
    for (int i = 0; i < 4; ++i) {
      fg = __builtin_amdgcn_fdot2(A1.h[i], Wf2[i + 4], fg, false);
      ig = __builtin_amdgcn_fdot2(A1.h[i], Wi2[i + 4], ig, false);
      hd = __builtin_amdgcn_fdot2(A1.h[i], Wh2[i + 4], hd, false);
    }
    const float diff  = spf_fast(-fg) - spf_fast(-ig);
    const float log_f = -spf_fast(diff);
    const float log_i = diff + log_f;          // sp(-d) = sp(d) - d
    const float lpos  = LN2_ * __builtin_amdgcn_logf(hd + 0.5f + EPS_);
    const float lneg  = -spf_fast(-hd) + EPS_;
    const float log_th = (hd >= 0.0f) ? lpos : lneg;
    p += log_f + EPS_;
    const float v = log_i + log_th - p;
    const float m = fmaxf(Mx, v);
    Ss = Ss * __builtin_amdgcn_exp2f((Mx - m) * LOG2E_)
       + __builtin_amdgcn_exp2f((v - m) * LOG2E_);
    Mx = m;
  }
  part[((size_t)(b * IN_ + g * 16 + o)) * NCH_ + ck] =
      make_float2(p, Mx + LN2_ * __builtin_amdgcn_logf(Ss));
}

// ---------------------------------------------------------------------------
// combine chunk partials -> h_last[b, c]
// ---------------------------------------------------------------------------
__launch_bounds__(256)
__global__ void combine_k(const float2* __restrict__ part, float* __restrict__ hlast)
{
  const int seq = blockIdx.x * 256 + threadIdx.x;
  if (seq >= B_ * IN_) return;
  const float2* pp = part + (size_t)seq * NCH_;
  float P = 0.0f, Mx = -INFINITY, Ss = 0.0f;
  for (int c = 0; c < NCH_; ++c) {
    const float2 al = pp[c];
    const float v = al.y - P;
    const float m = fmaxf(Mx, v);
    Ss = Ss * __builtin_amdgcn_exp2f((Mx - m) * LOG2E_)
       + __builtin_amdgcn_exp2f((v - m) * LOG2E_);
    Mx = m;
    P += al.x;
  }
  hlast[seq] = __builtin_amdgcn_exp2f((P + Mx) * LOG2E_) * Ss;
}

// ---------------------------------------------------------------------------
// G = (h_last + skip*act) * silu(z), written in place over the z buffer.
// ---------------------------------------------------------------------------
__launch_bounds__(256)
__global__ void gfuse_k(const unsigned* __restrict__ actb,
                        unsigned* __restrict__ zb,
                        const float* __restrict__ hlast,
                        const float* __restrict__ skipv)
{
  const size_t total  = (size_t)B_ * S_ * IN_ / 8;
  const size_t stride = (size_t)gridDim.x * blockDim.x;
  for (size_t t = (size_t)blockIdx.x * blockDim.x + threadIdx.x; t < total; t += stride) {
    const size_t e = t * 8;
    const int    c = (int)(e % IN_);
    const int    b = (int)(e / ((size_t)S_ * IN_));
    float a[8], z[8], hl[8], sk[8];
    unpack_h8(*(const uint4*)(actb + e / 2), a);
    unpack_h8(*(const uint4*)(zb   + e / 2), z);
    *(float4*)(hl)     = *(const float4*)(hlast + (size_t)b * IN_ + c);
    *(float4*)(hl + 4) = *(const float4*)(hlast + (size_t)b * IN_ + c + 4);
    *(float4*)(sk)     = *(const float4*)(skipv + c);
    *(float4*)(sk + 4) = *(const float4*)(skipv + c + 4);
    float g[8];
    #pragma unroll
    for (int j = 0; j < 8; ++j) g[j] = (hl[j] + sk[j] * a[j]) * z[j];
    uint4 o;
    o.x = packh2(g[0], g[1]);
    o.y = packh2(g[2], g[3]);
    o.z = packh2(g[4], g[5]);
    o.w = packh2(g[6], g[7]);
    *(uint4*)(zb + e / 2) = o;
  }
}

// ---------------------------------------------------------------------------
extern "C" void kernel_launch(void* const* d_in, const int* in_sizes, int n_in,
                              void* d_out, int out_size, void* d_ws, size_t ws_size,
                              hipStream_t stream)
{
  const float* x     = (const float*)d_in[0];
  const float* w_up  = (const float*)d_in[1];
  const float* b_up  = (const float*)d_in[2];
  const float* cw    = (const float*)d_in[3];
  const float* cb    = (const float*)d_in[4];
  const float* skipv = (const float*)d_in[5];
  const float* w_f   = (const float*)d_in[6];
  const float* w_i   = (const float*)d_in[7];
  const float* w_h   = (const float*)d_in[8];
  const float* w_dn  = (const float*)d_in[9];
  const float* b_dn  = (const float*)d_in[10];
  float* out = (float*)d_out;

  // workspace layout with lifetime-based aliasing (max ~210 MB):
  //  [0,   67M): xminb (dead after conv) -> then wdb @0 (4MB),
  //              part @8.39M (8.39MB), hlast @16.78M (32KB)
  //  [67M, 134M): zb (silu(z) -> G in place)
  //  [134M,201M): actb;  xb (f16 x, 33.5M) aliases this region (dead pre-conv)
  //  [201M,210M): wub (8.4MB)
  char* ws = (char*)d_ws;
  unsigned short* xminb = (unsigned short*)(ws);
  unsigned short* wdb   = (unsigned short*)(ws);                    // after conv
  float2*         part  = (float2*)(ws + 8388608ULL);               // after conv
  float*          hlast = (float*)(ws + 16777216ULL);               // after conv
  unsigned short* zb    = (unsigned short*)(ws + 67108864ULL);
  unsigned short* actb  = (unsigned short*)(ws + 134217728ULL);
  unsigned short* xb    = (unsigned short*)(ws + 134217728ULL);     // pre-conv alias
  unsigned short* wub   = (unsigned short*)(ws + 201326592ULL);

  const int M = B_ * S_;   // 16384

  // 0) fp32 -> f16 conversions for MFMA operands
  cvt_f16<<<2048, 256, 0, stream>>>(x,    (unsigned*)xb,  (long)M * D_ / 8);
  cvt_f16<<<512,  256, 0, stream>>>(w_up, (unsigned*)wub, (long)2 * IN_ * D_ / 8);

  // 1) proj-up: xb @ wub^T + b_up -> xmin(f16) | silu(z)(f16)
  gemm_mfma<0><<<dim3((2 * IN_) / 256, M / 256), 512, 0, stream>>>(
      xb, wub, b_up, xminb, (unsigned short*)zb, M, 2 * IN_, D_);

  // 2) causal depthwise conv + SiLU -> act(f16)
  conv_silu_k<<<2048, 256, 0, stream>>>((const unsigned*)xminb, cw, cb, (unsigned*)actb);

  // 2b) w_down -> f16 (into region freed by xminb)
  cvt_f16<<<256, 256, 0, stream>>>(w_dn, (unsigned*)wdb, (long)D_ * IN_ / 8);

  // 3) grouped gate projections + chunked scan partials
  gates_scan<<<(B_ * 128 * 16 * NCH_) / 256, 256, 0, stream>>>(
      (const unsigned*)actb, w_f, w_i, w_h, part);

  // 4) combine partials -> h_last
  combine_k<<<(B_ * IN_ + 255) / 256, 256, 0, stream>>>(part, hlast);

  // 5) G = (h_last + skip*act) * silu(z), in place over zb
  gfuse_k<<<2048, 256, 0, stream>>>((const unsigned*)actb, (unsigned*)zb, hlast, skipv);

  // 6) proj-down: G(f16) @ wdb^T + b_dn -> out (fp32)
  gemm_mfma<1><<<dim3(D_ / 256, M / 256), 512, 0, stream>>>(
      zb, wdb, b_dn, out, nullptr, M, D_, IN_);
}

// Round 7
// 511.858 us; speedup vs baseline: 6.0186x; 1.0584x over previous
//
#include <hip/hip_runtime.h>
#include <math.h>

// ---- problem constants (from reference) ----
constexpr int B_  = 4;
constexpr int S_  = 4096;
constexpr int D_  = 1024;   // DIM
constexpr int IN_ = 2048;   // INNER
constexpr float EPS_ = 1e-8f;
constexpr int NCH_ = 128;         // chunks per sequence for the scan
constexpr int CS_  = S_ / NCH_;   // 32 timesteps per chunk
constexpr float LOG2E_ = 1.4426950408889634f;
constexpr float LN2_   = 0.6931471805599453f;

typedef __attribute__((ext_vector_type(8))) _Float16 f16x8;
typedef __attribute__((ext_vector_type(2))) _Float16 h2;
typedef __attribute__((ext_vector_type(4))) float    f32x4;

#define BAR() asm volatile("s_barrier" ::: "memory")

// ---- helpers ----
__device__ __forceinline__ h2 pkrtz(float a, float b) {
  auto r = __builtin_amdgcn_cvt_pkrtz(a, b);
  union { decltype(r) r_; h2 h; } c; c.r_ = r; return c.h;
}
__device__ __forceinline__ unsigned packh2(float a, float b) {
  auto r = __builtin_amdgcn_cvt_pkrtz(a, b);
  union { decltype(r) r_; unsigned u; } c; c.r_ = r; return c.u;
}
__device__ __forceinline__ void unpack_h8(uint4 v, float* f) {
  union { uint4 u; _Float16 h[8]; } c; c.u = v;
  #pragma unroll
  for (int i = 0; i < 8; ++i) f[i] = (float)c.h[i];
}
__device__ __forceinline__ float spf_fast(float t) {       // softplus log(1+e^t)
  const float e = __builtin_amdgcn_exp2f(-fabsf(t) * LOG2E_);
  return fmaxf(t, 0.0f) + LN2_ * __builtin_amdgcn_logf(1.0f + e);
}
__device__ __forceinline__ float siluf(float x) {
  return x * __builtin_amdgcn_rcpf(1.0f + __builtin_amdgcn_exp2f(-x * LOG2E_));
}

// async global->LDS, 16 B per lane (wave-uniform LDS base + lane*16)
__device__ __forceinline__ void gload16(const void* g, void* l) {
  __builtin_amdgcn_global_load_lds(
      (const __attribute__((address_space(1))) void*)g,
      (__attribute__((address_space(3))) void*)l,
      16, 0, 0);
}

// ---------------------------------------------------------------------------
// fp32 -> f16 conversion (8 elems/thread)
// ---------------------------------------------------------------------------
__launch_bounds__(256)
__global__ void cvt_f16(const float* __restrict__ in, unsigned* __restrict__ outp,
                        long n8)
{
  const long stride = (long)gridDim.x * blockDim.x;
  for (long i = (long)blockIdx.x * blockDim.x + threadIdx.x; i < n8; i += stride) {
    const float4 a = *(const float4*)(in + i * 8);
    const float4 b = *(const float4*)(in + i * 8 + 4);
    uint4 o;
    o.x = packh2(a.x, a.y);
    o.y = packh2(a.z, a.w);
    o.z = packh2(b.x, b.y);
    o.w = packh2(b.z, b.w);
    *(uint4*)(outp + i * 4) = o;
  }
}

// ---------------------------------------------------------------------------
// f16 MFMA NT GEMM, 8-phase-style schedule:
//   256x256 tile, BK=64, 8 waves (2M x 4N), per-wave C = 128x64 (8x4 frags).
//   Double-buffered LDS (128 KiB), XOR-16B-block swizzle (blk ^= row&7)
//   applied via pre-swizzled GLOBAL source (linear global_load_lds dest) and
//   the same XOR on ds_read. 4 phases per K-tile, counted vmcnt(8), setprio.
// MODE 0: split epilogue -> xmin(f16) | silu(z)(f16) via per-wave LDS
//         transpose (16B stores, full-line writes, no RFO).
// MODE 1: fp32 out, direct stores (already 64B-contiguous per 16 lanes).
// ---------------------------------------------------------------------------
template<int MODE>
__launch_bounds__(512, 2)
__global__ void gemm_mfma(const unsigned short* __restrict__ Ab,
                          const unsigned short* __restrict__ Bb,
                          const float* __restrict__ bias,
                          void* __restrict__ out0,
                          unsigned short* __restrict__ out1,
                          int M, int N, int K)
{
  constexpr int BM = 256, BN = 256, BK = 64;
  __shared__ __align__(16) unsigned short As[2][BM * BK];  // 2 x 32 KB
  __shared__ __align__(16) unsigned short Bs[2][BN * BK];  // 2 x 32 KB

  const int tid  = threadIdx.x;
  const int lane = tid & 63;
  const int w    = tid >> 6;       // 0..7
  const int wm   = w >> 2;         // 0..1  (M half)
  const int wn   = w & 3;          // 0..3  (N quarter)
  const int m0 = blockIdx.y * BM;
  const int n0 = blockIdx.x * BN;
  const int NT = K / BK;

  // staging geometry: one call = 64 rows; wave w covers rows c*64+w*8 .. +7
  const int sr   = lane >> 3;                   // 0..7 row-in-slice
  const int sblk = ((lane & 7) ^ sr) * 8;       // pre-swizzled global col (elems)

  // fragment read geometry: row&7 == lane&7 for all fragment rows
  const int fr  = lane & 15;
  const int fb0 = (((lane >> 4) + 0) ^ (lane & 7)) * 8;   // k-step 0
  const int fb1 = (((lane >> 4) + 4) ^ (lane & 7)) * 8;   // k-step 1

  auto stage64 = [&](const unsigned short* Gp, int Kd, int grow0, int kOff,
                     unsigned short* lchunk) {
    gload16(Gp + (size_t)(grow0 + w * 8 + sr) * Kd + kOff + sblk,
            lchunk + (w * 8) * BK);
  };

  f32x4 acc[8][4] = {};

  // ---- prologue: stage tiles 0 and 1 ----
  #pragma unroll
  for (int c = 0; c < 4; ++c) stage64(Ab, K, m0 + c * 64, 0, &As[0][c * 64 * BK]);
  #pragma unroll
  for (int c = 0; c < 4; ++c) stage64(Bb, K, n0 + c * 64, 0, &Bs[0][c * 64 * BK]);
  #pragma unroll
  for (int c = 0; c < 4; ++c) stage64(Ab, K, m0 + c * 64, BK, &As[1][c * 64 * BK]);
  #pragma unroll
  for (int c = 0; c < 4; ++c) stage64(Bb, K, n0 + c * 64, BK, &Bs[1][c * 64 * BK]);
  asm volatile("s_waitcnt vmcnt(8)" ::: "memory");   // tile 0 landed
  BAR();

  for (int t = 0; t < NT; ++t) {
    const int cur = t & 1;
    const unsigned short* AL = As[cur];
    const unsigned short* BL = Bs[cur];
    const int  nxtK = (t + 2) * BK;
    const bool more = (t + 2 < NT);

    f16x8 af[4][2], bf[4][2];

    // ---- phase 0: quadrant (mq=0, nq=0) — 12 ds_reads, 16 MFMA
    #pragma unroll
    for (int i = 0; i < 4; ++i) {
      const int row = wm * 128 + i * 16 + fr;
      af[i][0] = *(const f16x8*)&AL[row * BK + fb0];
      af[i][1] = *(const f16x8*)&AL[row * BK + fb1];
    }
    #pragma unroll
    for (int j = 0; j < 2; ++j) {
      const int row = wn * 64 + j * 16 + fr;
      bf[j][0] = *(const f16x8*)&BL[row * BK + fb0];
      bf[j][1] = *(const f16x8*)&BL[row * BK + fb1];
    }
    BAR();
    __builtin_amdgcn_s_setprio(1);
    #pragma unroll
    for (int i = 0; i < 4; ++i)
      #pragma unroll
      for (int j = 0; j < 2; ++j) {
        acc[i][j] = __builtin_amdgcn_mfma_f32_16x16x32_f16(af[i][0], bf[j][0], acc[i][j], 0, 0, 0);
        acc[i][j] = __builtin_amdgcn_mfma_f32_16x16x32_f16(af[i][1], bf[j][1], acc[i][j], 0, 0, 0);
      }
    __builtin_amdgcn_s_setprio(0);
    BAR();

    // ---- phase 1: (mq=0, nq=1) — 4 ds_reads, 16 MFMA
    #pragma unroll
    for (int j = 2; j < 4; ++j) {
      const int row = wn * 64 + j * 16 + fr;
      bf[j][0] = *(const f16x8*)&BL[row * BK + fb0];
      bf[j][1] = *(const f16x8*)&BL[row * BK + fb1];
    }
    BAR();
    __builtin_amdgcn_s_setprio(1);
    #pragma unroll
    for (int i = 0; i < 4; ++i)
      #pragma unroll
      for (int j = 2; j < 4; ++j) {
        acc[i][j] = __builtin_amdgcn_mfma_f32_16x16x32_f16(af[i][0], bf[j][0], acc[i][j], 0, 0, 0);
        acc[i][j] = __builtin_amdgcn_mfma_f32_16x16x32_f16(af[i][1], bf[j][1], acc[i][j], 0, 0, 0);
      }
    __builtin_amdgcn_s_setprio(0);
    BAR();

    // ---- phase 2: (mq=1, nq=0) — 8 ds_reads; stage B rows 0-127 of t+2
    #pragma unroll
    for (int i = 0; i < 4; ++i) {
      const int row = wm * 128 + 64 + i * 16 + fr;
      af[i][0] = *(const f16x8*)&AL[row * BK + fb0];
      af[i][1] = *(const f16x8*)&AL[row * BK + fb1];
    }
    if (more) {
      stage64(Bb, K, n0 +  0, nxtK, &Bs[cur][0]);
      stage64(Bb, K, n0 + 64, nxtK, &Bs[cur][64 * BK]);
    }
    BAR();
    __builtin_amdgcn_s_setprio(1);
    #pragma unroll
    for (int i = 0; i < 4; ++i)
      #pragma unroll
      for (int j = 0; j < 2; ++j) {
        acc[4 + i][j] = __builtin_amdgcn_mfma_f32_16x16x32_f16(af[i][0], bf[j][0], acc[4 + i][j], 0, 0, 0);
        acc[4 + i][j] = __builtin_amdgcn_mfma_f32_16x16x32_f16(af[i][1], bf[j][1], acc[4 + i][j], 0, 0, 0);
      }
    __builtin_amdgcn_s_setprio(0);
    BAR();

    // ---- phase 3: (mq=1, nq=1) — 0 ds_reads; stage B rows 128-255 + all A of t+2
    if (more) {
      stage64(Bb, K, n0 + 128, nxtK, &Bs[cur][128 * BK]);
      stage64(Bb, K, n0 + 192, nxtK, &Bs[cur][192 * BK]);
      #pragma unroll
      for (int c = 0; c < 4; ++c) stage64(Ab, K, m0 + c * 64, nxtK, &As[cur][c * 64 * BK]);
    }
    BAR();
    __builtin_amdgcn_s_setprio(1);
    #pragma unroll
    for (int i = 0; i < 4; ++i)
      #pragma unroll
      for (int j = 2; j < 4; ++j) {
        acc[4 + i][j] = __builtin_amdgcn_mfma_f32_16x16x32_f16(af[i][0], bf[j][0], acc[4 + i][j], 0, 0, 0);
        acc[4 + i][j] = __builtin_amdgcn_mfma_f32_16x16x32_f16(af[i][1], bf[j][1], acc[4 + i][j], 0, 0, 0);
      }
    __builtin_amdgcn_s_setprio(0);
    if (more) asm volatile("s_waitcnt vmcnt(8)" ::: "memory");
    else      asm volatile("s_waitcnt vmcnt(0)" ::: "memory");
    BAR();
  }

  // ---- epilogue ----
  const int col = lane & 15;
  const int rb4 = (lane >> 4) * 4;

  if (MODE == 1) {
    // fp32 direct stores: lanes 0-15 cover 64B contiguous per row
    #pragma unroll
    for (int j = 0; j < 4; ++j) {
      const int n  = n0 + wn * 64 + j * 16 + col;
      const float bv = bias[n];
      #pragma unroll
      for (int i = 0; i < 8; ++i) {
        const int mb = m0 + wm * 128 + i * 16 + rb4;
        #pragma unroll
        for (int r = 0; r < 4; ++r)
          ((float*)out0)[(size_t)(mb + r) * N + n] = acc[i][j][r] + bv;
      }
    }
  } else {
    // f16 split outputs via per-wave LDS transpose -> 16B full-line stores.
    // Wave-private slice: 64 rows x RS(=72) f16 (9216 B); waves 0-3 in As,
    // waves 4-7 in Bs. Two 64-row halves reuse the slice. No barriers needed.
    constexpr int RS = 72;
    unsigned short* eb = (w < 4) ? ((unsigned short*)As + w * (64 * RS))
                                 : ((unsigned short*)Bs + (w - 4) * (64 * RS));
    const bool zhalf = (n0 >= IN_);   // block-uniform: n-tiles don't straddle
    float bv[4];
    #pragma unroll
    for (int j = 0; j < 4; ++j) bv[j] = bias[n0 + wn * 64 + j * 16 + col];

    const int lrow = lane >> 3;
    const int lc8  = (lane & 7) * 8;
    unsigned short* dst = zhalf ? out1 : (unsigned short*)out0;
    const int ncol0 = (zhalf ? n0 - IN_ : n0) + wn * 64 + lc8;

    #pragma unroll
    for (int h = 0; h < 2; ++h) {
      asm volatile("s_waitcnt lgkmcnt(0)" ::: "memory");  // slice reusable
      #pragma unroll
      for (int i2 = 0; i2 < 4; ++i2)
        #pragma unroll
        for (int j = 0; j < 4; ++j)
          #pragma unroll
          for (int r = 0; r < 4; ++r) {
            const float v = acc[h * 4 + i2][j][r] + bv[j];
            ((_Float16*)eb)[(i2 * 16 + rb4 + r) * RS + j * 16 + col] = (_Float16)v;
          }
      asm volatile("s_waitcnt lgkmcnt(0)" ::: "memory");
      #pragma unroll
      for (int it = 0; it < 8; ++it) {
        const int row = it * 8 + lrow;
        uint4 d = *(const uint4*)&eb[row * RS + lc8];
        if (zhalf) {
          float f[8];
          unpack_h8(d, f);
          d.x = packh2(siluf(f[0]), siluf(f[1]));
          d.y = packh2(siluf(f[2]), siluf(f[3]));
          d.z = packh2(siluf(f[4]), siluf(f[5]));
          d.w = packh2(siluf(f[6]), siluf(f[7]));
        }
        const int m = m0 + wm * 128 + h * 64 + row;
        *(uint4*)(dst + (size_t)m * IN_ + ncol0) = d;
      }
    }
  }
}

// ---------------------------------------------------------------------------
// causal depthwise conv (K=4, left pad 3) + SiLU.  f16 in/out, 8 ch/thread.
// ---------------------------------------------------------------------------
__launch_bounds__(256)
__global__ void conv_silu_k(const unsigned* __restrict__ xm,
                            const float* __restrict__ cw,   // (IN_,1,4)
                            const float* __restrict__ cb,
                            unsigned* __restrict__ act)
{
  const size_t total  = (size_t)B_ * S_ * IN_ / 8;
  const size_t stride = (size_t)gridDim.x * blockDim.x;
  for (size_t t = (size_t)blockIdx.x * blockDim.x + threadIdx.x; t < total; t += stride) {
    const size_t e = t * 8;
    const int    c  = (int)(e % IN_);
    const size_t bs = e / IN_;          // b*S_ + s
    const int    s  = (int)(bs % S_);
    float w[8][4];
    #pragma unroll
    for (int j = 0; j < 8; ++j)
      *(float4*)w[j] = *(const float4*)(cw + (size_t)(c + j) * 4);
    float r[8];
    *(float4*)(r)     = *(const float4*)(cb + c);
    *(float4*)(r + 4) = *(const float4*)(cb + c + 4);
    #pragma unroll
    for (int k = 0; k < 4; ++k) {
      const int ss = s - 3 + k;
      if (ss >= 0) {
        const uint4 xv = *(const uint4*)(xm + ((size_t)bs + k - 3) * (IN_ / 2) + c / 2);
        float xf[8];
        unpack_h8(xv, xf);
        #pragma unroll
        for (int j = 0; j < 8; ++j) r[j] = fmaf(xf[j], w[j][k], r[j]);
      }
    }
    uint4 o;
    o.x = packh2(siluf(r[0]), siluf(r[1]));
    o.y = packh2(siluf(r[2]), siluf(r[3]));
    o.z = packh2(siluf(r[4]), siluf(r[5]));
    o.w = packh2(siluf(r[6]), siluf(r[7]));
    *(uint4*)(act + e / 2) = o;
  }
}

// ---------------------------------------------------------------------------
// grouped 16x16 gate projections + per-chunk scan partials.
// act in f16; dots via v_dot2_f32_f16; fast exp2/log2 log-math; branchless LSE.
// ---------------------------------------------------------------------------
__launch_bounds__(256)
__global__ void gates_scan(const unsigned* __restrict__ actb,
                           const float* __restrict__ wf,
                           const float* __restrict__ wi,
                           const float* __restrict__ wh,
                           float2* __restrict__ part)   // [B_*IN_][NCH_]
{
  const int T  = blockIdx.x * 256 + threadIdx.x;
  const int o  = T & 15;
  const int g  = (T >> 4) & 127;
  const int ck = (T >> 11) & (NCH_ - 1);
  const int b  = T >> 18;

  h2 Wf2[8], Wi2[8], Wh2[8];
  const float* pf = wf + ((size_t)g * 16 + o) * 16;
  const float* pi = wi + ((size_t)g * 16 + o) * 16;
  const float* ph = wh + ((size_t)g * 16 + o) * 16;
  #pragma unroll
  for (int i = 0; i < 8; ++i) {
    Wf2[i] = pkrtz(pf[2 * i], pf[2 * i + 1]);
    Wi2[i] = pkrtz(pi[2 * i], pi[2 * i + 1]);
    Wh2[i] = pkrtz(ph[2 * i], ph[2 * i + 1]);
  }

  float p = 0.0f, Mx = -INFINITY, Ss = 0.0f;
  const unsigned* ap = actb + ((size_t)b * S_ + (size_t)ck * CS_) * (IN_ / 2) + g * 8;
  for (int s = 0; s < CS_; ++s) {
    union { uint4 u; h2 h[4]; } A0, A1;
    A0.u = *(const uint4*)(ap);
    A1.u = *(const uint4*)(ap + 4);
    ap += IN_ / 2;
    float fg = 0.0f, ig = 0.0f, hd = 0.0f;
    #pragma unroll
    for (int i = 0; i < 4; ++i) {
      fg = __builtin_amdgcn_fdot2(A0.h[i], Wf2[i], fg, false);
      ig = __builtin_amdgcn_fdot2(A0.h[i], Wi2[i], ig, false);
      hd = __builtin_amdgcn_fdot2(A0.h[i], Wh2[i], hd, false);
    }
    #pragma unroll
    for (int i = 0; i < 4; ++i) {
      fg = __builtin_amdgcn_fdot2(A1.h[i], Wf2[i + 4], fg, false);
      ig = __builtin_amdgcn_fdot2(A1.h[i], Wi2[i + 4], ig, false);
      hd = __builtin_amdgcn_fdot2(A1.h[i], Wh2[i + 4], hd, false);
    }
    const float diff  = spf_fast(-fg) - spf_fast(-ig);
    const float log_f = -spf_fast(diff);
    const float log_i = diff + log_f;          // sp(-d) = sp(d) - d
    const float lpos  = LN2_ * __builtin_amdgcn_logf(hd + 0.5f + EPS_);
    const float lneg  = -spf_fast(-hd) + EPS_;
    const float log_th = (hd >= 0.0f) ? lpos : lneg;
    p += log_f + EPS_;
    const float v = log_i + log_th - p;
    const float m = fmaxf(Mx, v);
    Ss = Ss * __builtin_amdgcn_exp2f((Mx - m) * LOG2E_)
       + __builtin_amdgcn_exp2f((v - m) * LOG2E_);
    Mx = m;
  }
  part[((size_t)(b * IN_ + g * 16 + o)) * NCH_ + ck] =
      make_float2(p, Mx + LN2_ * __builtin_amdgcn_logf(Ss));
}

// ---------------------------------------------------------------------------
// combine chunk partials -> h_last[b, c]
// ---------------------------------------------------------------------------
__launch_bounds__(256)
__global__ void combine_k(const float2* __restrict__ part, float* __restrict__ hlast)
{
  const int seq = blockIdx.x * 256 + threadIdx.x;
  if (seq >= B_ * IN_) return;
  const float2* pp = part + (size_t)seq * NCH_;
  float P = 0.0f, Mx = -INFINITY, Ss = 0.0f;
  for (int c = 0; c < NCH_; ++c) {
    const float2 al = pp[c];
    const float v = al.y - P;
    const float m = fmaxf(Mx, v);
    Ss = Ss * __builtin_amdgcn_exp2f((Mx - m) * LOG2E_)
       + __builtin_amdgcn_exp2f((v - m) * LOG2E_);
    Mx = m;
    P += al.x;
  }
  hlast[seq] = __builtin_amdgcn_exp2f((P + Mx) * LOG2E_) * Ss;
}

// ---------------------------------------------------------------------------
// G = (h_last + skip*act) * silu(z), written in place over the z buffer.
// ---------------------------------------------------------------------------
__launch_bounds__(256)
__global__ void gfuse_k(const unsigned* __restrict__ actb,
                        unsigned* __restrict__ zb,
                        const float* __restrict__ hlast,
                        const float* __restrict__ skipv)
{
  const size_t total  = (size_t)B_ * S_ * IN_ / 8;
  const size_t stride = (size_t)gridDim.x * blockDim.x;
  for (size_t t = (size_t)blockIdx.x * blockDim.x + threadIdx.x; t < total; t += stride) {
    const size_t e = t * 8;
    const int    c = (int)(e % IN_);
    const int    b = (int)(e / ((size_t)S_ * IN_));
    float a[8], z[8], hl[8], sk[8];
    unpack_h8(*(const uint4*)(actb + e / 2), a);
    unpack_h8(*(const uint4*)(zb   + e / 2), z);
    *(float4*)(hl)     = *(const float4*)(hlast + (size_t)b * IN_ + c);
    *(float4*)(hl + 4) = *(const float4*)(hlast + (size_t)b * IN_ + c + 4);
    *(float4*)(sk)     = *(const float4*)(skipv + c);
    *(float4*)(sk + 4) = *(const float4*)(skipv + c + 4);
    float g[8];
    #pragma unroll
    for (int j = 0; j < 8; ++j) g[j] = (hl[j] + sk[j] * a[j]) * z[j];
    uint4 o;
    o.x = packh2(g[0], g[1]);
    o.y = packh2(g[2], g[3]);
    o.z = packh2(g[4], g[5]);
    o.w = packh2(g[6], g[7]);
    *(uint4*)(zb + e / 2) = o;
  }
}

// ---------------------------------------------------------------------------
extern "C" void kernel_launch(void* const* d_in, const int* in_sizes, int n_in,
                              void* d_out, int out_size, void* d_ws, size_t ws_size,
                              hipStream_t stream)
{
  const float* x     = (const float*)d_in[0];
  const float* w_up  = (const float*)d_in[1];
  const float* b_up  = (const float*)d_in[2];
  const float* cw    = (const float*)d_in[3];
  const float* cb    = (const float*)d_in[4];
  const float* skipv = (const float*)d_in[5];
  const float* w_f   = (const float*)d_in[6];
  const float* w_i   = (const float*)d_in[7];
  const float* w_h   = (const float*)d_in[8];
  const float* w_dn  = (const float*)d_in[9];
  const float* b_dn  = (const float*)d_in[10];
  float* out = (float*)d_out;

  // workspace layout with lifetime-based aliasing (max ~210 MB):
  //  [0,   67M): xminb (dead after conv) -> then wdb @0 (4MB),
  //              part @8.39M (8.39MB), hlast @16.78M (32KB)
  //  [67M, 134M): zb (silu(z) -> G in place)
  //  [134M,201M): actb;  xb (f16 x, 33.5M) aliases this region (dead pre-conv)
  //  [201M,210M): wub (8.4MB)
  char* ws = (char*)d_ws;
  unsigned short* xminb = (unsigned short*)(ws);
  unsigned short* wdb   = (unsigned short*)(ws);                    // after conv
  float2*         part  = (float2*)(ws + 8388608ULL);               // after conv
  float*          hlast = (float*)(ws + 16777216ULL);               // after conv
  unsigned short* zb    = (unsigned short*)(ws + 67108864ULL);
  unsigned short* actb  = (unsigned short*)(ws + 134217728ULL);
  unsigned short* xb    = (unsigned short*)(ws + 134217728ULL);     // pre-conv alias
  unsigned short* wub   = (unsigned short*)(ws + 201326592ULL);

  const int M = B_ * S_;   // 16384

  // 0) fp32 -> f16 conversions for MFMA operands
  cvt_f16<<<2048, 256, 0, stream>>>(x,    (unsigned*)xb,  (long)M * D_ / 8);
  cvt_f16<<<512,  256, 0, stream>>>(w_up, (unsigned*)wub, (long)2 * IN_ * D_ / 8);

  // 1) proj-up: xb @ wub^T + b_up -> xmin(f16) | silu(z)(f16)
  gemm_mfma<0><<<dim3((2 * IN_) / 256, M / 256), 512, 0, stream>>>(
      xb, wub, b_up, xminb, (unsigned short*)zb, M, 2 * IN_, D_);

  // 2) causal depthwise conv + SiLU -> act(f16)
  conv_silu_k<<<2048, 256, 0, stream>>>((const unsigned*)xminb, cw, cb, (unsigned*)actb);

  // 2b) w_down -> f16 (into region freed by xminb)
  cvt_f16<<<256, 256, 0, stream>>>(w_dn, (unsigned*)wdb, (long)D_ * IN_ / 8);

  // 3) grouped gate projections + chunked scan partials
  gates_scan<<<(B_ * 128 * 16 * NCH_) / 256, 256, 0, stream>>>(
      (const unsigned*)actb, w_f, w_i, w_h, part);

  // 4) combine partials -> h_last
  combine_k<<<(B_ * IN_ + 255) / 256, 256, 0, stream>>>(part, hlast);

  // 5) G = (h_last + skip*act) * silu(z), in place over zb
  gfuse_k<<<2048, 256, 0, stream>>>((const unsigned*)actb, (unsigned*)zb, hlast, skipv);

  // 6) proj-down: G(f16) @ wdb^T + b_dn -> out (fp32)
  gemm_mfma<1><<<dim3(D_ / 256, M / 256), 512, 0, stream>>>(
      zb, wdb, b_dn, out, nullptr, M, D_, IN_);
}